// Round 1
// baseline (857.057 us; speedup 1.0000x reference)
//
#include <hip/hip_runtime.h>
#include <hip/hip_bf16.h>
#include <stdint.h>

#define BATCH 4
#define NPTS  4096
#define DIM   128
#define KNN   16
#define NROWS (BATCH*NPTS)   // 16384

// ---------------- prep: pad pos (B,N,3) -> float4 ----------------
__global__ __launch_bounds__(256) void prep_pos4(const float* __restrict__ pos,
                                                 float4* __restrict__ pos4) {
  int i = blockIdx.x * 256 + threadIdx.x;
  if (i < NROWS) {
    pos4[i] = make_float4(pos[3*i], pos[3*i+1], pos[3*i+2], 0.f);
  }
}

// ---------------- kNN: top-16 smallest squared distance ----------------
// block = 256 thr = 4 waves. Block handles 64 queries (lane <-> query).
// Wave w scans candidate chunk [w*1024, w*1024+1024) keeping sorted top-16
// on packed keys: (fp64-dist bits truncated to 52 high bits) | 12-bit idx.
// fp64 is near-exact for fp32 inputs -> ordering matches a float64 numpy ref;
// idx in low bits gives top_k's ascending-index tie-break for free.
__global__ __launch_bounds__(256) void knn_kernel(const float4* __restrict__ pos4,
                                                  int* __restrict__ knn) {
  __shared__ unsigned long long lds[4][64][17];  // pad 17 to break bank stride
  const int lane  = threadIdx.x & 63;
  const int w     = threadIdx.x >> 6;
  const int qbase = blockIdx.x * 64;   // all 64 queries in same batch (4096%64==0)
  const int b     = qbase >> 12;       // /NPTS
  const int q     = qbase + lane;

  float4 qp = pos4[q];
  double qx = qp.x, qy = qp.y, qz = qp.z;

  unsigned long long key[KNN];
#pragma unroll
  for (int p = 0; p < KNN; ++p) key[p] = ~0ull;

  const float4* cand = pos4 + b*NPTS + w*1024;
  const unsigned long long jb = (unsigned long long)(w*1024);
#pragma unroll 4
  for (int j = 0; j < 1024; ++j) {
    float4 p = cand[j];                      // uniform addr -> scalar/broadcast
    double dx = qx - (double)p.x;
    double dy = qy - (double)p.y;
    double dz = qz - (double)p.z;
    double d  = dx*dx + dy*dy + dz*dz;       // >= 0, bits monotone as u64
    unsigned long long kk =
        (((unsigned long long)__double_as_longlong(d)) & ~0xFFFull) | (jb + j);
    if (kk < key[KNN-1]) {                   // rare; gated bubble insert
      unsigned long long cur = kk;
#pragma unroll
      for (int p2 = 0; p2 < KNN; ++p2) {
        unsigned long long mn = key[p2] < cur ? key[p2] : cur;
        cur   = key[p2] < cur ? cur : key[p2];
        key[p2] = mn;
      }
    }
  }
#pragma unroll
  for (int p = 0; p < KNN; ++p) lds[w][lane][p] = key[p];
  __syncthreads();

  if (threadIdx.x < 64) {            // merge 4 sorted lists -> global top-16
    const int t = threadIdx.x;
    int i0 = 0, i1 = 0, i2 = 0, i3 = 0;
    const int outq = (qbase + t) * KNN;
#pragma unroll
    for (int s = 0; s < KNN; ++s) {
      unsigned long long v0 = lds[0][t][i0];
      unsigned long long v1 = lds[1][t][i1];
      unsigned long long v2 = lds[2][t][i2];
      unsigned long long v3 = lds[3][t][i3];
      unsigned long long m01 = v0 < v1 ? v0 : v1;
      unsigned long long m23 = v2 < v3 ? v2 : v3;
      unsigned long long m   = m01 < m23 ? m01 : m23;
      i0 += (m == v0); i1 += (m == v1); i2 += (m == v2); i3 += (m == v3);
      knn[outq + s] = (int)(m & 0xFFFull);
    }
  }
}

// ---------------- fused q/K/V projection: 16384x128 @ 128x128 (x3) ----------------
// block = 256 thr handles 32 rows; thread (g=tid>>7, c=tid&127) computes 16 rows
// for channel c for all three projections.
__global__ __launch_bounds__(256) void proj_kernel(const float* __restrict__ x,
    const float* __restrict__ qw, const float* __restrict__ qb,
    const float* __restrict__ kw, const float* __restrict__ kb,
    const float* __restrict__ vw, const float* __restrict__ vb,
    float* __restrict__ qo, float* __restrict__ ko, float* __restrict__ vo) {
  __shared__ float xs[32*DIM];
  const int row0 = blockIdx.x * 32;
  const int c = threadIdx.x & (DIM-1);
  const int g = threadIdx.x >> 7;     // 0,1

  for (int i = threadIdx.x; i < 32*DIM; i += 256) xs[i] = x[row0*DIM + i];
  __syncthreads();

  float aq[16], ak[16], av[16];
#pragma unroll
  for (int r = 0; r < 16; ++r) { aq[r] = 0.f; ak[r] = 0.f; av[r] = 0.f; }

  for (int d4 = 0; d4 < DIM/4; ++d4) {
    float wq[4], wk[4], wv[4];
#pragma unroll
    for (int t = 0; t < 4; ++t) {
      int d = d4*4 + t;
      wq[t] = qw[d*DIM + c];
      wk[t] = kw[d*DIM + c];
      wv[t] = vw[d*DIM + c];
    }
#pragma unroll
    for (int r = 0; r < 16; ++r) {
      float4 xv = *(const float4*)&xs[(g*16+r)*DIM + d4*4];
      float xe[4]; xe[0]=xv.x; xe[1]=xv.y; xe[2]=xv.z; xe[3]=xv.w;
#pragma unroll
      for (int t = 0; t < 4; ++t) {
        aq[r] = fmaf(xe[t], wq[t], aq[r]);
        ak[r] = fmaf(xe[t], wk[t], ak[r]);
        av[r] = fmaf(xe[t], wv[t], av[r]);
      }
    }
  }
  const float bq = qb[c], bk = kb[c], bv = vb[c];
#pragma unroll
  for (int r = 0; r < 16; ++r) {
    int row = row0 + g*16 + r;
    qo[row*DIM + c] = aq[r] + bq;
    ko[row*DIM + c] = ak[r] + bk;
    vo[row*DIM + c] = av[r] + bv;
  }
}

// ---------------- fused attention ----------------
// block = 256 thr = 2 sub-blocks of 128; each sub-block owns one query.
// LDS buffers reused across phases: h1s holds h1 then pe; as_ holds a then logits.
__global__ __launch_bounds__(256) void attn_kernel(
    const float4* __restrict__ pos4,
    const int*    __restrict__ knn,
    const float*  __restrict__ qws, const float* __restrict__ kws, const float* __restrict__ vws,
    const float*  __restrict__ pw1, const float* __restrict__ pb1,
    const float*  __restrict__ pw2, const float* __restrict__ pb2,
    const float*  __restrict__ aw1, const float* __restrict__ ab1,
    const float*  __restrict__ aw2, const float* __restrict__ ab2,
    float* __restrict__ out) {
  __shared__ float h1s[2][KNN][DIM];   // h1, then pe
  __shared__ float as_[2][KNN][DIM];   // a, then logits
  __shared__ float h2s[2][KNN][32];
  __shared__ float rels[2][KNN][4];
  __shared__ int   idxs[2][KNN];

  const int sb   = threadIdx.x >> 7;            // 0/1
  const int st   = threadIdx.x & 127;
  const int qrow = blockIdx.x * 2 + sb;         // 0..16383
  const int b    = qrow >> 12;

  // setup: neighbor indices + relative positions
  if (st < KNN) {
    int id = knn[qrow*KNN + st];
    idxs[sb][st] = id;
    float4 pq = pos4[qrow];
    float4 pn = pos4[b*NPTS + id];
    rels[sb][st][0] = pq.x - pn.x;
    rels[sb][st][1] = pq.y - pn.y;
    rels[sb][st][2] = pq.z - pn.z;
    rels[sb][st][3] = 0.f;
  }
  __syncthreads();

  // phase 1: h1[k][c] = relu(rel @ pw1 + pb1)   (thread = channel st)
  {
    float w0 = pw1[st], w1 = pw1[DIM+st], w2 = pw1[2*DIM+st], bb = pb1[st];
#pragma unroll
    for (int k = 0; k < KNN; ++k) {
      float4 r = *(const float4*)&rels[sb][k][0];
      float v = fmaf(r.x, w0, fmaf(r.y, w1, fmaf(r.z, w2, bb)));
      h1s[sb][k][st] = v > 0.f ? v : 0.f;
    }
  }
  __syncthreads();

  // phase 2: pe = h1 @ pw2 + pb2 ; 4x4 register tile per thread
  const int kg = st >> 5;        // 0..3  (k-group)
  const int cg = st & 31;        // c-group
  const int c0 = cg * 4;
  float pe[4][4];
#pragma unroll
  for (int i = 0; i < 4; ++i)
#pragma unroll
    for (int j = 0; j < 4; ++j) pe[i][j] = 0.f;

  for (int d4 = 0; d4 < DIM/4; ++d4) {
    float h[4][4];
#pragma unroll
    for (int i = 0; i < 4; ++i) {
      float4 t4 = *(const float4*)&h1s[sb][kg*4+i][d4*4];
      h[i][0]=t4.x; h[i][1]=t4.y; h[i][2]=t4.z; h[i][3]=t4.w;
    }
#pragma unroll
    for (int t = 0; t < 4; ++t) {
      float4 wv = *(const float4*)&pw2[(d4*4+t)*DIM + c0];
#pragma unroll
      for (int i = 0; i < 4; ++i) {
        pe[i][0] = fmaf(h[i][t], wv.x, pe[i][0]);
        pe[i][1] = fmaf(h[i][t], wv.y, pe[i][1]);
        pe[i][2] = fmaf(h[i][t], wv.z, pe[i][2]);
        pe[i][3] = fmaf(h[i][t], wv.w, pe[i][3]);
      }
    }
  }
  {
    float4 bp = *(const float4*)&pb2[c0];
#pragma unroll
    for (int i = 0; i < 4; ++i) {
      pe[i][0] += bp.x; pe[i][1] += bp.y; pe[i][2] += bp.z; pe[i][3] += bp.w;
    }
  }

  // phase 3: a = q - k + pe  (register tile; global gathers coalesced per row)
  float at[4][4];
  {
    float4 qv = *(const float4*)&qws[qrow*DIM + c0];
#pragma unroll
    for (int i = 0; i < 4; ++i) {
      int id = idxs[sb][kg*4+i];
      float4 kv = *(const float4*)&kws[(b*NPTS+id)*DIM + c0];
      at[i][0] = qv.x - kv.x + pe[i][0];
      at[i][1] = qv.y - kv.y + pe[i][1];
      at[i][2] = qv.z - kv.z + pe[i][2];
      at[i][3] = qv.w - kv.w + pe[i][3];
    }
  }
  __syncthreads();   // h1s reads (phase 2) done everywhere

  // phase 4: stash pe -> h1s, a -> as_
#pragma unroll
  for (int i = 0; i < 4; ++i) {
    *(float4*)&h1s[sb][kg*4+i][c0] = make_float4(pe[i][0], pe[i][1], pe[i][2], pe[i][3]);
    *(float4*)&as_[sb][kg*4+i][c0] = make_float4(at[i][0], at[i][1], at[i][2], at[i][3]);
  }
  __syncthreads();

  // phase 5: h2[k][j] = relu(a @ aw1 + ab1), j<32. thread = (kq = st>>5, jj = st&31)
  {
    const int kq = st >> 5;
    const int jj = st & 31;
    float h2a[4] = {0.f, 0.f, 0.f, 0.f};
    for (int c4 = 0; c4 < DIM/4; ++c4) {
      float a_[4][4];
#pragma unroll
      for (int i = 0; i < 4; ++i) {
        float4 t4 = *(const float4*)&as_[sb][kq*4+i][c4*4];
        a_[i][0]=t4.x; a_[i][1]=t4.y; a_[i][2]=t4.z; a_[i][3]=t4.w;
      }
#pragma unroll
      for (int t = 0; t < 4; ++t) {
        float wv = aw1[(c4*4+t)*32 + jj];
#pragma unroll
        for (int i = 0; i < 4; ++i) h2a[i] = fmaf(a_[i][t], wv, h2a[i]);
      }
    }
    float bb = ab1[jj];
#pragma unroll
    for (int i = 0; i < 4; ++i) {
      float v = h2a[i] + bb;
      h2s[sb][kq*4+i][jj] = v > 0.f ? v : 0.f;
    }
  }
  __syncthreads();

  // phase 6: logits = h2 @ aw2 + ab2 ; 4x4 tile, store into as_
  {
    float lg[4][4];
#pragma unroll
    for (int i = 0; i < 4; ++i)
#pragma unroll
      for (int j = 0; j < 4; ++j) lg[i][j] = 0.f;
    for (int j4 = 0; j4 < 8; ++j4) {
      float hh[4][4];
#pragma unroll
      for (int i = 0; i < 4; ++i) {
        float4 t4 = *(const float4*)&h2s[sb][kg*4+i][j4*4];
        hh[i][0]=t4.x; hh[i][1]=t4.y; hh[i][2]=t4.z; hh[i][3]=t4.w;
      }
#pragma unroll
      for (int t = 0; t < 4; ++t) {
        float4 wv = *(const float4*)&aw2[(j4*4+t)*DIM + c0];
#pragma unroll
        for (int i = 0; i < 4; ++i) {
          lg[i][0] = fmaf(hh[i][t], wv.x, lg[i][0]);
          lg[i][1] = fmaf(hh[i][t], wv.y, lg[i][1]);
          lg[i][2] = fmaf(hh[i][t], wv.z, lg[i][2]);
          lg[i][3] = fmaf(hh[i][t], wv.w, lg[i][3]);
        }
      }
    }
    float4 b2 = *(const float4*)&ab2[c0];
#pragma unroll
    for (int i = 0; i < 4; ++i) {
      lg[i][0] += b2.x; lg[i][1] += b2.y; lg[i][2] += b2.z; lg[i][3] += b2.w;
      *(float4*)&as_[sb][kg*4+i][c0] = make_float4(lg[i][0], lg[i][1], lg[i][2], lg[i][3]);
    }
  }
  __syncthreads();

  // phase 7: per-channel softmax over k, weighted sum of (V + pe)
  {
    const int c = st;
    float lo[KNN];
#pragma unroll
    for (int k = 0; k < KNN; ++k) lo[k] = as_[sb][k][c];
    float m = lo[0];
#pragma unroll
    for (int k = 1; k < KNN; ++k) m = fmaxf(m, lo[k]);
    float e[KNN]; float s = 0.f;
#pragma unroll
    for (int k = 0; k < KNN; ++k) { e[k] = __expf(lo[k] - m); s += e[k]; }
    float inv = 1.0f / s;
    float acc = 0.f;
#pragma unroll
    for (int k = 0; k < KNN; ++k) {
      int id = idxs[sb][k];
      float vv = vws[(b*NPTS+id)*DIM + c];
      float pev = h1s[sb][k][c];
      acc = fmaf(e[k]*inv, vv + pev, acc);
    }
    out[qrow*DIM + c] = acc;
  }
}

// ---------------- launch ----------------
extern "C" void kernel_launch(void* const* d_in, const int* in_sizes, int n_in,
                              void* d_out, int out_size, void* d_ws, size_t ws_size,
                              hipStream_t stream) {
  const float* x   = (const float*)d_in[0];
  const float* pos = (const float*)d_in[1];
  const float* pw1 = (const float*)d_in[2];
  const float* pb1 = (const float*)d_in[3];
  const float* pw2 = (const float*)d_in[4];
  const float* pb2 = (const float*)d_in[5];
  const float* qw  = (const float*)d_in[6];
  const float* qb  = (const float*)d_in[7];
  const float* kw  = (const float*)d_in[8];
  const float* kb  = (const float*)d_in[9];
  const float* vw  = (const float*)d_in[10];
  const float* vb  = (const float*)d_in[11];
  const float* aw1 = (const float*)d_in[12];
  const float* ab1 = (const float*)d_in[13];
  const float* aw2 = (const float*)d_in[14];
  const float* ab2 = (const float*)d_in[15];
  float* out = (float*)d_out;

  char* ws = (char*)d_ws;
  float4* pos4 = (float4*)(ws);                       // 256 KB
  int*    knn  = (int*)(ws + (1u<<20));               // 1 MB
  float*  qws  = (float*)(ws + (2u<<20));             // 8 MB
  float*  kws  = (float*)(ws + (10u<<20));            // 8 MB
  float*  vws  = (float*)(ws + (18u<<20));            // 8 MB  (total 26 MB)

  prep_pos4<<<NROWS/256, 256, 0, stream>>>(pos, pos4);
  knn_kernel<<<NROWS/64, 256, 0, stream>>>(pos4, knn);
  proj_kernel<<<NROWS/32, 256, 0, stream>>>(x, qw, qb, kw, kb, vw, vb, qws, kws, vws);
  attn_kernel<<<NROWS/2, 256, 0, stream>>>(pos4, knn, qws, kws, vws,
                                           pw1, pb1, pw2, pb2, aw1, ab1, aw2, ab2, out);
}

// Round 2
// 490.402 us; speedup vs baseline: 1.7477x; 1.7477x over previous
//
#include <hip/hip_runtime.h>
#include <hip/hip_bf16.h>
#include <stdint.h>

#define BATCH 4
#define NPTS  4096
#define DIM   128
#define KNN   16
#define NROWS (BATCH*NPTS)   // 16384
#define NCHUNK 16
#define CHUNK  (NPTS/NCHUNK) // 256

typedef unsigned long long u64;

// ---------------- prep: pad pos (B,N,3) -> float4 ----------------
__global__ __launch_bounds__(256) void prep_pos4(const float* __restrict__ pos,
                                                 float4* __restrict__ pos4) {
  int i = blockIdx.x * 256 + threadIdx.x;
  if (i < NROWS) {
    pos4[i] = make_float4(pos[3*i], pos[3*i+1], pos[3*i+2], 0.f);
  }
}

// ---------------- branchless sorting primitives on u64 keys ----------------
__device__ __forceinline__ void cex(u64& a, u64& b) {
  u64 mn = a < b ? a : b;
  u64 mx = a < b ? b : a;
  a = mn; b = mx;
}

// ascending bitonic sort of 16 (static network, 80 CE)
__device__ __forceinline__ void sort16(u64 x[16]) {
#pragma unroll
  for (int k = 2; k <= 16; k <<= 1) {
#pragma unroll
    for (int j = k >> 1; j > 0; j >>= 1) {
#pragma unroll
      for (int i = 0; i < 16; ++i) {
        int l = i ^ j;
        if (l > i) {
          if ((i & k) == 0) cex(x[i], x[l]);
          else              cex(x[l], x[i]);
        }
      }
    }
  }
}

// A asc, B asc -> A = smallest 16 of A∪B, ascending (half-cleaner + bitonic sort)
__device__ __forceinline__ void merge16(u64 A[16], const u64 B[16]) {
#pragma unroll
  for (int i = 0; i < 16; ++i) {
    u64 b = B[15 - i];
    A[i] = A[i] < b ? A[i] : b;
  }
#pragma unroll
  for (int j = 8; j > 0; j >>= 1) {
#pragma unroll
    for (int i = 0; i < 16; ++i) {
      int l = i ^ j;
      if (l > i) cex(A[i], A[l]);
    }
  }
}

// ---------------- kNN pass 1: per-(query, 256-candidate-chunk) sorted top-16 ----------------
// block = 256 thr = 4 waves; each wave = one task (64-query group x one chunk).
// lane <-> query. Keys: (fp64 dist bits & ~0xFFF) | idx  (proven ordering, round 1).
__global__ __launch_bounds__(256) void knn_scan(const float4* __restrict__ pos4,
                                                u64* __restrict__ part) {
  __shared__ float4 cs[4][CHUNK];   // 4 waves x 4 KB
  const int lane  = threadIdx.x & 63;
  const int w     = threadIdx.x >> 6;
  const int task  = blockIdx.x * 4 + w;     // 0..4095
  const int qg    = task >> 4;              // 0..255
  const int chunk = task & 15;              // 0..15
  const int qbase = qg * 64;
  const int b     = qbase >> 12;            // batch
  const int cbase = chunk * CHUNK;

  // stage this wave's candidate chunk into LDS (coalesced)
  const float4* cand = pos4 + b*NPTS + cbase;
#pragma unroll
  for (int i = 0; i < 4; ++i) cs[w][lane + 64*i] = cand[lane + 64*i];
  __syncthreads();

  float4 qp = pos4[qbase + lane];
  const double qx = qp.x, qy = qp.y, qz = qp.z;

  u64 best[16];
#pragma unroll
  for (int i = 0; i < 16; ++i) best[i] = ~0ull;

#pragma unroll 1
  for (int m = 0; m < CHUNK/16; ++m) {
    u64 batch[16];
#pragma unroll
    for (int e = 0; e < 16; ++e) {
      float4 p = cs[w][m*16 + e];           // uniform addr -> LDS broadcast
      double dx = qx - (double)p.x;
      double dy = qy - (double)p.y;
      double dz = qz - (double)p.z;
      double d  = fma(dx, dx, fma(dy, dy, dz*dz));
      batch[e] = (((u64)__double_as_longlong(d)) & ~0xFFFull)
               | (u64)(cbase + m*16 + e);
    }
    sort16(batch);
    merge16(best, batch);
  }

  // store sorted list: part[(chunk*16 + s)*NROWS + q]  (coalesced across lanes)
  const int q = qbase + lane;
#pragma unroll
  for (int s = 0; s < 16; ++s) part[(chunk*16 + s)*NROWS + q] = best[s];
}

// ---------------- kNN pass 2: merge 16 sorted lists per query ----------------
__global__ __launch_bounds__(256) void knn_merge(const u64* __restrict__ part,
                                                 int* __restrict__ knn) {
  const int q = blockIdx.x * 256 + threadIdx.x;   // 0..16383
  u64 best[16];
#pragma unroll
  for (int s = 0; s < 16; ++s) best[s] = part[s*NROWS + q];
#pragma unroll 1
  for (int c = 1; c < NCHUNK; ++c) {
    u64 nb[16];
#pragma unroll
    for (int s = 0; s < 16; ++s) nb[s] = part[(c*16 + s)*NROWS + q];
    merge16(best, nb);
  }
#pragma unroll
  for (int s = 0; s < 16; ++s) knn[q*KNN + s] = (int)(best[s] & 0xFFFull);
}

// ---------------- fused q/K/V projection: 16384x128 @ 128x128 (x3) ----------------
__global__ __launch_bounds__(256) void proj_kernel(const float* __restrict__ x,
    const float* __restrict__ qw, const float* __restrict__ qb,
    const float* __restrict__ kw, const float* __restrict__ kb,
    const float* __restrict__ vw, const float* __restrict__ vb,
    float* __restrict__ qo, float* __restrict__ ko, float* __restrict__ vo) {
  __shared__ float xs[32*DIM];
  const int row0 = blockIdx.x * 32;
  const int c = threadIdx.x & (DIM-1);
  const int g = threadIdx.x >> 7;     // 0,1

  for (int i = threadIdx.x; i < 32*DIM; i += 256) xs[i] = x[row0*DIM + i];
  __syncthreads();

  float aq[16], ak[16], av[16];
#pragma unroll
  for (int r = 0; r < 16; ++r) { aq[r] = 0.f; ak[r] = 0.f; av[r] = 0.f; }

  for (int d4 = 0; d4 < DIM/4; ++d4) {
    float wq[4], wk[4], wv[4];
#pragma unroll
    for (int t = 0; t < 4; ++t) {
      int d = d4*4 + t;
      wq[t] = qw[d*DIM + c];
      wk[t] = kw[d*DIM + c];
      wv[t] = vw[d*DIM + c];
    }
#pragma unroll
    for (int r = 0; r < 16; ++r) {
      float4 xv = *(const float4*)&xs[(g*16+r)*DIM + d4*4];
      float xe[4]; xe[0]=xv.x; xe[1]=xv.y; xe[2]=xv.z; xe[3]=xv.w;
#pragma unroll
      for (int t = 0; t < 4; ++t) {
        aq[r] = fmaf(xe[t], wq[t], aq[r]);
        ak[r] = fmaf(xe[t], wk[t], ak[r]);
        av[r] = fmaf(xe[t], wv[t], av[r]);
      }
    }
  }
  const float bq = qb[c], bk = kb[c], bv = vb[c];
#pragma unroll
  for (int r = 0; r < 16; ++r) {
    int row = row0 + g*16 + r;
    qo[row*DIM + c] = aq[r] + bq;
    ko[row*DIM + c] = ak[r] + bk;
    vo[row*DIM + c] = av[r] + bv;
  }
}

// ---------------- fused attention ----------------
__global__ __launch_bounds__(256) void attn_kernel(
    const float4* __restrict__ pos4,
    const int*    __restrict__ knn,
    const float*  __restrict__ qws, const float* __restrict__ kws, const float* __restrict__ vws,
    const float*  __restrict__ pw1, const float* __restrict__ pb1,
    const float*  __restrict__ pw2, const float* __restrict__ pb2,
    const float*  __restrict__ aw1, const float* __restrict__ ab1,
    const float*  __restrict__ aw2, const float* __restrict__ ab2,
    float* __restrict__ out) {
  __shared__ float h1s[2][KNN][DIM];   // h1, then pe
  __shared__ float as_[2][KNN][DIM];   // a, then logits
  __shared__ float h2s[2][KNN][32];
  __shared__ float rels[2][KNN][4];
  __shared__ int   idxs[2][KNN];

  const int sb   = threadIdx.x >> 7;            // 0/1
  const int st   = threadIdx.x & 127;
  const int qrow = blockIdx.x * 2 + sb;         // 0..16383
  const int b    = qrow >> 12;

  if (st < KNN) {
    int id = knn[qrow*KNN + st];
    idxs[sb][st] = id;
    float4 pq = pos4[qrow];
    float4 pn = pos4[b*NPTS + id];
    rels[sb][st][0] = pq.x - pn.x;
    rels[sb][st][1] = pq.y - pn.y;
    rels[sb][st][2] = pq.z - pn.z;
    rels[sb][st][3] = 0.f;
  }
  __syncthreads();

  // phase 1: h1[k][c] = relu(rel @ pw1 + pb1)
  {
    float w0 = pw1[st], w1 = pw1[DIM+st], w2 = pw1[2*DIM+st], bb = pb1[st];
#pragma unroll
    for (int k = 0; k < KNN; ++k) {
      float4 r = *(const float4*)&rels[sb][k][0];
      float v = fmaf(r.x, w0, fmaf(r.y, w1, fmaf(r.z, w2, bb)));
      h1s[sb][k][st] = v > 0.f ? v : 0.f;
    }
  }
  __syncthreads();

  // phase 2: pe = h1 @ pw2 + pb2
  const int kg = st >> 5;
  const int cg = st & 31;
  const int c0 = cg * 4;
  float pe[4][4];
#pragma unroll
  for (int i = 0; i < 4; ++i)
#pragma unroll
    for (int j = 0; j < 4; ++j) pe[i][j] = 0.f;

  for (int d4 = 0; d4 < DIM/4; ++d4) {
    float h[4][4];
#pragma unroll
    for (int i = 0; i < 4; ++i) {
      float4 t4 = *(const float4*)&h1s[sb][kg*4+i][d4*4];
      h[i][0]=t4.x; h[i][1]=t4.y; h[i][2]=t4.z; h[i][3]=t4.w;
    }
#pragma unroll
    for (int t = 0; t < 4; ++t) {
      float4 wv = *(const float4*)&pw2[(d4*4+t)*DIM + c0];
#pragma unroll
      for (int i = 0; i < 4; ++i) {
        pe[i][0] = fmaf(h[i][t], wv.x, pe[i][0]);
        pe[i][1] = fmaf(h[i][t], wv.y, pe[i][1]);
        pe[i][2] = fmaf(h[i][t], wv.z, pe[i][2]);
        pe[i][3] = fmaf(h[i][t], wv.w, pe[i][3]);
      }
    }
  }
  {
    float4 bp = *(const float4*)&pb2[c0];
#pragma unroll
    for (int i = 0; i < 4; ++i) {
      pe[i][0] += bp.x; pe[i][1] += bp.y; pe[i][2] += bp.z; pe[i][3] += bp.w;
    }
  }

  // phase 3: a = q - k + pe
  float at[4][4];
  {
    float4 qv = *(const float4*)&qws[qrow*DIM + c0];
#pragma unroll
    for (int i = 0; i < 4; ++i) {
      int id = idxs[sb][kg*4+i];
      float4 kv = *(const float4*)&kws[(b*NPTS+id)*DIM + c0];
      at[i][0] = qv.x - kv.x + pe[i][0];
      at[i][1] = qv.y - kv.y + pe[i][1];
      at[i][2] = qv.z - kv.z + pe[i][2];
      at[i][3] = qv.w - kv.w + pe[i][3];
    }
  }
  __syncthreads();

  // phase 4: stash pe -> h1s, a -> as_
#pragma unroll
  for (int i = 0; i < 4; ++i) {
    *(float4*)&h1s[sb][kg*4+i][c0] = make_float4(pe[i][0], pe[i][1], pe[i][2], pe[i][3]);
    *(float4*)&as_[sb][kg*4+i][c0] = make_float4(at[i][0], at[i][1], at[i][2], at[i][3]);
  }
  __syncthreads();

  // phase 5: h2 = relu(a @ aw1 + ab1), 32 cols
  {
    const int kq = st >> 5;
    const int jj = st & 31;
    float h2a[4] = {0.f, 0.f, 0.f, 0.f};
    for (int c4 = 0; c4 < DIM/4; ++c4) {
      float a_[4][4];
#pragma unroll
      for (int i = 0; i < 4; ++i) {
        float4 t4 = *(const float4*)&as_[sb][kq*4+i][c4*4];
        a_[i][0]=t4.x; a_[i][1]=t4.y; a_[i][2]=t4.z; a_[i][3]=t4.w;
      }
#pragma unroll
      for (int t = 0; t < 4; ++t) {
        float wv = aw1[(c4*4+t)*32 + jj];
#pragma unroll
        for (int i = 0; i < 4; ++i) h2a[i] = fmaf(a_[i][t], wv, h2a[i]);
      }
    }
    float bb = ab1[jj];
#pragma unroll
    for (int i = 0; i < 4; ++i) {
      float v = h2a[i] + bb;
      h2s[sb][kq*4+i][jj] = v > 0.f ? v : 0.f;
    }
  }
  __syncthreads();

  // phase 6: logits = h2 @ aw2 + ab2
  {
    float lg[4][4];
#pragma unroll
    for (int i = 0; i < 4; ++i)
#pragma unroll
      for (int j = 0; j < 4; ++j) lg[i][j] = 0.f;
    for (int j4 = 0; j4 < 8; ++j4) {
      float hh[4][4];
#pragma unroll
      for (int i = 0; i < 4; ++i) {
        float4 t4 = *(const float4*)&h2s[sb][kg*4+i][j4*4];
        hh[i][0]=t4.x; hh[i][1]=t4.y; hh[i][2]=t4.z; hh[i][3]=t4.w;
      }
#pragma unroll
      for (int t = 0; t < 4; ++t) {
        float4 wv = *(const float4*)&aw2[(j4*4+t)*DIM + c0];
#pragma unroll
        for (int i = 0; i < 4; ++i) {
          lg[i][0] = fmaf(hh[i][t], wv.x, lg[i][0]);
          lg[i][1] = fmaf(hh[i][t], wv.y, lg[i][1]);
          lg[i][2] = fmaf(hh[i][t], wv.z, lg[i][2]);
          lg[i][3] = fmaf(hh[i][t], wv.w, lg[i][3]);
        }
      }
    }
    float4 b2 = *(const float4*)&ab2[c0];
#pragma unroll
    for (int i = 0; i < 4; ++i) {
      lg[i][0] += b2.x; lg[i][1] += b2.y; lg[i][2] += b2.z; lg[i][3] += b2.w;
      *(float4*)&as_[sb][kg*4+i][c0] = make_float4(lg[i][0], lg[i][1], lg[i][2], lg[i][3]);
    }
  }
  __syncthreads();

  // phase 7: per-channel softmax over k, weighted sum of (V + pe)
  {
    const int c = st;
    float lo[KNN];
#pragma unroll
    for (int k = 0; k < KNN; ++k) lo[k] = as_[sb][k][c];
    float m = lo[0];
#pragma unroll
    for (int k = 1; k < KNN; ++k) m = fmaxf(m, lo[k]);
    float e[KNN]; float s = 0.f;
#pragma unroll
    for (int k = 0; k < KNN; ++k) { e[k] = __expf(lo[k] - m); s += e[k]; }
    float inv = 1.0f / s;
    float acc = 0.f;
#pragma unroll
    for (int k = 0; k < KNN; ++k) {
      int id = idxs[sb][k];
      float vv = vws[(b*NPTS+id)*DIM + c];
      float pev = h1s[sb][k][c];
      acc = fmaf(e[k]*inv, vv + pev, acc);
    }
    out[qrow*DIM + c] = acc;
  }
}

// ---------------- launch ----------------
extern "C" void kernel_launch(void* const* d_in, const int* in_sizes, int n_in,
                              void* d_out, int out_size, void* d_ws, size_t ws_size,
                              hipStream_t stream) {
  const float* x   = (const float*)d_in[0];
  const float* pos = (const float*)d_in[1];
  const float* pw1 = (const float*)d_in[2];
  const float* pb1 = (const float*)d_in[3];
  const float* pw2 = (const float*)d_in[4];
  const float* pb2 = (const float*)d_in[5];
  const float* qw  = (const float*)d_in[6];
  const float* qb  = (const float*)d_in[7];
  const float* kw  = (const float*)d_in[8];
  const float* kb  = (const float*)d_in[9];
  const float* vw  = (const float*)d_in[10];
  const float* vb  = (const float*)d_in[11];
  const float* aw1 = (const float*)d_in[12];
  const float* ab1 = (const float*)d_in[13];
  const float* aw2 = (const float*)d_in[14];
  const float* ab2 = (const float*)d_in[15];
  float* out = (float*)d_out;

  char* ws = (char*)d_ws;
  float4* pos4 = (float4*)(ws);                 // 256 KB
  int*    knn  = (int*)(ws + (1u<<20));         // 1 MB
  // part (33.5 MB) lives at 2 MB and is DEAD before proj writes qws/kws/vws
  u64*    part = (u64*)(ws + (2u<<20));
  float*  qws  = (float*)(ws + (2u<<20));       // reused after knn_merge
  float*  kws  = (float*)(ws + (10u<<20));
  float*  vws  = (float*)(ws + (18u<<20));

  prep_pos4<<<NROWS/256, 256, 0, stream>>>(pos, pos4);
  knn_scan<<<(NROWS/64)*NCHUNK/4, 256, 0, stream>>>(pos4, part);
  knn_merge<<<NROWS/256, 256, 0, stream>>>(part, knn);
  proj_kernel<<<NROWS/32, 256, 0, stream>>>(x, qw, qb, kw, kb, vw, vb, qws, kws, vws);
  attn_kernel<<<NROWS/2, 256, 0, stream>>>(pos4, knn, qws, kws, vws,
                                           pw1, pb1, pw2, pb2, aw1, ab1, aw2, ab2, out);
}

// Round 3
// 303.783 us; speedup vs baseline: 2.8213x; 1.6143x over previous
//
#include <hip/hip_runtime.h>
#include <hip/hip_bf16.h>
#include <stdint.h>

#define BATCH 4
#define NPTS  4096
#define DIM   128
#define KNN   16
#define NROWS (BATCH*NPTS)   // 16384
#define NCHUNK 8
#define CHUNK  (NPTS/NCHUNK) // 512

typedef unsigned long long u64;
typedef unsigned int u32;
typedef unsigned short u16;
typedef __attribute__((ext_vector_type(8))) short short8;
typedef __attribute__((ext_vector_type(4))) float f32x4;

__device__ __forceinline__ u16 f2bf(float f) {
  u32 u = __float_as_uint(f);
  u += 0x7FFFu + ((u >> 16) & 1);   // RNE
  return (u16)(u >> 16);
}

// ---------------- prep: pad pos (B,N,3) -> float4 ----------------
__global__ __launch_bounds__(256) void prep_pos4(const float* __restrict__ pos,
                                                 float4* __restrict__ pos4) {
  int i = blockIdx.x * 256 + threadIdx.x;
  if (i < NROWS) pos4[i] = make_float4(pos[3*i], pos[3*i+1], pos[3*i+2], 0.f);
}

// ---------------- prep: folded weight products ----------------
// W1 = pw2@aw1 (bf16, transposed+swizzled); Wq2 = qw@aw1, Wk2 = kw@aw1 (f32)
__global__ __launch_bounds__(256) void prep_matmul(
    const float* __restrict__ pw2, const float* __restrict__ qw, const float* __restrict__ kw,
    const float* __restrict__ aw1,
    u16* __restrict__ w1T, float* __restrict__ Wq2, float* __restrict__ Wk2) {
  int p = blockIdx.x >> 2, qtr = blockIdx.x & 3;
  const float* A = p == 0 ? pw2 : (p == 1 ? qw : kw);
  int j = threadIdx.x & 31;
  int r0 = qtr*32 + (threadIdx.x >> 5)*4;
  float acc[4] = {0.f,0.f,0.f,0.f};
  for (int c = 0; c < 128; ++c) {
    float av = aw1[c*32 + j];
#pragma unroll
    for (int rr = 0; rr < 4; ++rr) acc[rr] = fmaf(A[(r0+rr)*128 + c], av, acc[rr]);
  }
#pragma unroll
  for (int rr = 0; rr < 4; ++rr) {
    int h = r0 + rr;
    if (p == 0)      w1T[j*128 + (h ^ ((j&7)<<3))] = f2bf(acc[rr]);
    else if (p == 1) Wq2[h*32 + j] = acc[rr];
    else             Wk2[h*32 + j] = acc[rr];
  }
}

// ---------------- prep: bf16 transposed/swizzled weight images + pw1 float4 + bias1 ----------------
__global__ __launch_bounds__(256) void prep_convert(
    const float* __restrict__ pw2, const float* __restrict__ aw2,
    const float* __restrict__ pw1, const float* __restrict__ pb1,
    const float* __restrict__ qb, const float* __restrict__ kb,
    const float* __restrict__ pb2, const float* __restrict__ aw1, const float* __restrict__ ab1,
    u16* __restrict__ pw2T, u16* __restrict__ aw2T,
    float4* __restrict__ pw1q, float* __restrict__ bias1) {
  int bid = blockIdx.x, tid = threadIdx.x;
  if (bid < 64) {                    // pw2T[n][k], 256B rows, swz (n&7)<<4 bytes
    int e = bid*256 + tid; int k = e >> 7, n = e & 127;
    pw2T[n*128 + (k ^ ((n&7)<<3))] = f2bf(pw2[k*128 + n]);
  } else if (bid < 80) {             // aw2T[n][k<32], 64B rows, swz (n&3)<<4 bytes
    int e = (bid-64)*256 + tid; int k = e >> 7, n = e & 127;
    aw2T[n*32 + (k ^ ((n&3)<<3))] = f2bf(aw2[k*128 + n]);
  } else {
    if (tid < 128) {                 // pw1q: (w0,w1,w2,pb1) per channel, bank-spread perm
      int c = tid;
      pw1q[c ^ ((c & 0x18) >> 2)] = make_float4(pw1[c], pw1[128+c], pw1[256+c], pb1[c]);
    } else if (tid < 160) {          // bias1 = (qb-kb+pb2)@aw1 + ab1
      int j = tid - 128;
      float s = ab1[j];
      for (int c = 0; c < 128; ++c) s += (qb[c]-kb[c]+pb2[c]) * aw1[c*32+j];
      bias1[j] = s;
    }
  }
}

// ---------------- branchless sorting primitives on u64 keys ----------------
__device__ __forceinline__ void cex(u64& a, u64& b) {
  u64 mn = a < b ? a : b;
  u64 mx = a < b ? b : a;
  a = mn; b = mx;
}
__device__ __forceinline__ void sort16(u64 x[16]) {
#pragma unroll
  for (int k = 2; k <= 16; k <<= 1)
#pragma unroll
    for (int j = k >> 1; j > 0; j >>= 1)
#pragma unroll
      for (int i = 0; i < 16; ++i) {
        int l = i ^ j;
        if (l > i) { if ((i & k) == 0) cex(x[i], x[l]); else cex(x[l], x[i]); }
      }
}
__device__ __forceinline__ void merge16(u64 A[16], const u64 B[16]) {
#pragma unroll
  for (int i = 0; i < 16; ++i) { u64 b = B[15 - i]; A[i] = A[i] < b ? A[i] : b; }
#pragma unroll
  for (int j = 8; j > 0; j >>= 1)
#pragma unroll
    for (int i = 0; i < 16; ++i) { int l = i ^ j; if (l > i) cex(A[i], A[l]); }
}

// ---------------- kNN pass 1 (fp64 keys, unchanged semantics) ----------------
__global__ __launch_bounds__(256) void knn_scan(const float4* __restrict__ pos4,
                                                u64* __restrict__ part) {
  __shared__ float4 cs[4][CHUNK];
  const int lane  = threadIdx.x & 63;
  const int w     = threadIdx.x >> 6;
  const int task  = blockIdx.x * 4 + w;     // 0..2047
  const int qg    = task >> 3;
  const int chunk = task & 7;
  const int qbase = qg * 64;
  const int b     = qbase >> 12;
  const int cbase = chunk * CHUNK;

  const float4* cand = pos4 + b*NPTS + cbase;
#pragma unroll
  for (int i = 0; i < CHUNK/64; ++i) cs[w][lane + 64*i] = cand[lane + 64*i];
  __syncthreads();

  float4 qp = pos4[qbase + lane];
  const double qx = qp.x, qy = qp.y, qz = qp.z;

  u64 best[16];
#pragma unroll
  for (int i = 0; i < 16; ++i) best[i] = ~0ull;

#pragma unroll 1
  for (int m = 0; m < CHUNK/16; ++m) {
    u64 batch[16];
#pragma unroll
    for (int e = 0; e < 16; ++e) {
      float4 p = cs[w][m*16 + e];
      double dx = qx - (double)p.x;
      double dy = qy - (double)p.y;
      double dz = qz - (double)p.z;
      double d  = fma(dx, dx, fma(dy, dy, dz*dz));
      batch[e] = (((u64)__double_as_longlong(d)) & ~0xFFFull) | (u64)(cbase + m*16 + e);
    }
    sort16(batch);
    merge16(best, batch);
  }
  const int q = qbase + lane;
#pragma unroll
  for (int s = 0; s < 16; ++s) part[(chunk*16 + s)*NROWS + q] = best[s];
}

// ---------------- kNN pass 2 ----------------
__global__ __launch_bounds__(256) void knn_merge(const u64* __restrict__ part,
                                                 int* __restrict__ knn) {
  const int q = blockIdx.x * 256 + threadIdx.x;
  u64 best[16];
#pragma unroll
  for (int s = 0; s < 16; ++s) best[s] = part[s*NROWS + q];
#pragma unroll 1
  for (int c = 1; c < NCHUNK; ++c) {
    u64 nb[16];
#pragma unroll
    for (int s = 0; s < 16; ++s) nb[s] = part[(c*16 + s)*NROWS + q];
    merge16(best, nb);
  }
#pragma unroll
  for (int s = 0; s < 16; ++s) knn[q*KNN + s] = (int)(best[s] & 0xFFFull);
}

// ---------------- proj: V + qa + ka ----------------
__global__ __launch_bounds__(256) void proj_v(
    const float* __restrict__ x,
    const float* __restrict__ vw, const float* __restrict__ vb,
    const float* __restrict__ Wq2, const float* __restrict__ Wk2,
    float* __restrict__ vo, float* __restrict__ qa, float* __restrict__ ka) {
  __shared__ float xs[32*DIM];
  const int row0 = blockIdx.x * 32;
  const int tid = threadIdx.x;
  {
    const float4* src = (const float4*)(x + row0*DIM);
    float4* dst = (float4*)xs;
#pragma unroll
    for (int i = 0; i < 4; ++i) dst[tid + 256*i] = src[tid + 256*i];
  }
  __syncthreads();
  { // V
    const int c = tid & 127, g2 = tid >> 7;
    float av[16];
#pragma unroll
    for (int r = 0; r < 16; ++r) av[r] = 0.f;
    for (int d4 = 0; d4 < 32; ++d4) {
      float wv[4];
#pragma unroll
      for (int t = 0; t < 4; ++t) wv[t] = vw[(d4*4+t)*DIM + c];
#pragma unroll
      for (int r = 0; r < 16; ++r) {
        float4 xv = *(const float4*)&xs[(g2*16+r)*DIM + d4*4];
        av[r] = fmaf(xv.x, wv[0], av[r]);
        av[r] = fmaf(xv.y, wv[1], av[r]);
        av[r] = fmaf(xv.z, wv[2], av[r]);
        av[r] = fmaf(xv.w, wv[3], av[r]);
      }
    }
    float bv = vb[c];
#pragma unroll
    for (int r = 0; r < 16; ++r) vo[(row0 + g2*16 + r)*DIM + c] = av[r] + bv;
  }
  { // qa/ka (32 cols)
    const int j = tid & 31, grp = tid >> 5;
    float aq[4] = {0.f,0.f,0.f,0.f}, ak[4] = {0.f,0.f,0.f,0.f};
    for (int d4 = 0; d4 < 32; ++d4) {
#pragma unroll
      for (int t = 0; t < 4; ++t) {
        int d = d4*4 + t;
        float wq = Wq2[d*32 + j], wk = Wk2[d*32 + j];
#pragma unroll
        for (int rr = 0; rr < 4; ++rr) {
          float xv = xs[(grp*4+rr)*DIM + d];
          aq[rr] = fmaf(xv, wq, aq[rr]);
          ak[rr] = fmaf(xv, wk, ak[rr]);
        }
      }
    }
#pragma unroll
    for (int rr = 0; rr < 4; ++rr) {
      qa[(row0 + grp*4 + rr)*32 + j] = aq[rr];
      ka[(row0 + grp*4 + rr)*32 + j] = ak[rr];
    }
  }
}

// ---------------- fused MFMA attention: one wave per query ----------------
__global__ __launch_bounds__(256) void attn_mfma(
    const float4* __restrict__ pos4, const int* __restrict__ knnIdx,
    const float* __restrict__ vws, const float* __restrict__ qa, const float* __restrict__ ka,
    const u16* __restrict__ pw2T, const u16* __restrict__ w1T, const u16* __restrict__ aw2T,
    const float4* __restrict__ pw1q, const float* __restrict__ bias1,
    const float* __restrict__ pb2, const float* __restrict__ ab2,
    float* __restrict__ out) {
  __shared__ __align__(16) u16 pw2s[16384];   // 32 KB
  __shared__ __align__(16) u16 w1s[4096];     // 8 KB
  __shared__ __align__(16) u16 aw2s[4096];    // 8 KB
  __shared__ __align__(16) float4 pw1s[128];  // 2 KB
  __shared__ float bias1s[32];
  __shared__ float pb2s[128];
  __shared__ float ab2s[128];
  __shared__ __align__(16) u16 h2t[4][512];   // per-wave 16x32 bf16, 64B rows, swz (row&3)<<4
  __shared__ float4 rels[4][16];
  __shared__ int ids[4][16];

  const int tid = threadIdx.x;
  { // stage weights (linear copies; source already transposed+swizzled)
    const uint4* s1 = (const uint4*)pw2T; uint4* d1 = (uint4*)pw2s;
#pragma unroll
    for (int i = 0; i < 8; ++i) d1[tid + 256*i] = s1[tid + 256*i];
    const uint4* s2 = (const uint4*)w1T; uint4* d2 = (uint4*)w1s;
#pragma unroll
    for (int i = 0; i < 2; ++i) d2[tid + 256*i] = s2[tid + 256*i];
    const uint4* s3 = (const uint4*)aw2T; uint4* d3 = (uint4*)aw2s;
#pragma unroll
    for (int i = 0; i < 2; ++i) d3[tid + 256*i] = s3[tid + 256*i];
    if (tid < 128) { pw1s[tid] = pw1q[tid]; pb2s[tid] = pb2[tid]; ab2s[tid] = ab2[tid]; }
    else if (tid < 160) bias1s[tid-128] = bias1[tid-128];
  }
  __syncthreads();

  const int lane = tid & 63, w = tid >> 6;
  const int c16 = lane & 15, g = lane >> 4;

  for (int it = 0; it < 4; ++it) {
    const int q = blockIdx.x*16 + w*4 + it;
    const int b = q >> 12;
    if (lane < 16) {
      int id = knnIdx[q*KNN + lane];
      ids[w][lane] = id;
      float4 pq = pos4[q], pn = pos4[(b<<12) + id];
      rels[w][lane] = make_float4(pq.x-pn.x, pq.y-pn.y, pq.z-pn.z, 0.f);
    }
    __syncthreads();

    int idr[4];
#pragma unroll
    for (int r = 0; r < 4; ++r) idr[r] = ids[w][g*4 + r];

    // early gathers (hide latency under h1/pe/ha)
    float qa_v[2], ka_v[2][4];
#pragma unroll
    for (int t = 0; t < 2; ++t) qa_v[t] = qa[q*32 + t*16 + c16];
#pragma unroll
    for (int r = 0; r < 4; ++r)
#pragma unroll
      for (int t = 0; t < 2; ++t) ka_v[t][r] = ka[((b<<12)+idr[r])*32 + t*16 + c16];

    // h1 in A-fragment layout: lane holds row=c16, k = kc*32 + g*8 + j
    float4 rl = rels[w][c16];
    short8 h1f[4];
#pragma unroll
    for (int kc = 0; kc < 4; ++kc) {
      short8 s;
#pragma unroll
      for (int j = 0; j < 8; ++j) {
        int c = kc*32 + g*8 + j;
        float4 wv = pw1s[c ^ ((c & 0x18) >> 2)];
        float h = fmaf(rl.x, wv.x, fmaf(rl.y, wv.y, fmaf(rl.z, wv.z, wv.w)));
        s[j] = (short)f2bf(fmaxf(h, 0.f));
      }
      h1f[kc] = s;
    }

    // pe = h1 @ pw2  (bias added at the end)
    f32x4 pe[8];
#pragma unroll
    for (int nt = 0; nt < 8; ++nt) { f32x4 z = {0.f,0.f,0.f,0.f}; pe[nt] = z; }
#pragma unroll
    for (int kc = 0; kc < 4; ++kc)
#pragma unroll
      for (int nt = 0; nt < 8; ++nt) {
        int n = nt*16 + c16;
        short8 bf = *(const short8*)&pw2s[n*128 + ((kc*32 + g*8) ^ ((n&7)<<3))];
        pe[nt] = __builtin_amdgcn_mfma_f32_16x16x32_bf16(h1f[kc], bf, pe[nt], 0, 0, 0);
      }

    // ha = h1 @ W1 (2 tiles of 16 cols)
    f32x4 ha[2];
#pragma unroll
    for (int t = 0; t < 2; ++t) { f32x4 z = {0.f,0.f,0.f,0.f}; ha[t] = z; }
#pragma unroll
    for (int kc = 0; kc < 4; ++kc)
#pragma unroll
      for (int t = 0; t < 2; ++t) {
        int n = t*16 + c16;
        short8 bf = *(const short8*)&w1s[n*128 + ((kc*32 + g*8) ^ ((n&7)<<3))];
        ha[t] = __builtin_amdgcn_mfma_f32_16x16x32_bf16(h1f[kc], bf, ha[t], 0, 0, 0);
      }

    // h2 = relu(ha + qa - ka + bias1) -> bf16 -> LDS (C-layout write, A-layout read)
#pragma unroll
    for (int t = 0; t < 2; ++t)
#pragma unroll
      for (int r = 0; r < 4; ++r) {
        float v = ha[t][r] + qa_v[t] - ka_v[t][r] + bias1s[t*16 + c16];
        int row = g*4 + r, col = t*16 + c16;
        h2t[w][row*32 + (col ^ ((row&3)<<3))] = f2bf(fmaxf(v, 0.f));
      }
    __syncthreads();

    short8 h2f = *(const short8*)&h2t[w][c16*32 + ((g*8) ^ ((c16&3)<<3))];

    // logits = h2 @ aw2 + ab2  (C preloaded with per-col bias)
    f32x4 lg[8];
#pragma unroll
    for (int nt = 0; nt < 8; ++nt) {
      int n = nt*16 + c16;
      float ab = ab2s[n];
      f32x4 cini = {ab, ab, ab, ab};
      short8 bf = *(const short8*)&aw2s[n*32 + ((g*8) ^ ((n&3)<<3))];
      lg[nt] = __builtin_amdgcn_mfma_f32_16x16x32_bf16(h2f, bf, cini, 0, 0, 0);
    }

    // V gather
    float vv[8][4];
#pragma unroll
    for (int r = 0; r < 4; ++r) {
      const float* vrow = vws + (size_t)((b<<12) + idr[r])*DIM;
#pragma unroll
      for (int nt = 0; nt < 8; ++nt) vv[nt][r] = vrow[nt*16 + c16];
    }

    // per-column softmax over 16 rows + weighted sum of (v + pe + pb2)
#pragma unroll
    for (int nt = 0; nt < 8; ++nt) {
      float m = fmaxf(fmaxf(lg[nt][0], lg[nt][1]), fmaxf(lg[nt][2], lg[nt][3]));
      m = fmaxf(m, __shfl_xor(m, 16));
      m = fmaxf(m, __shfl_xor(m, 32));
      float e0 = __expf(lg[nt][0]-m), e1 = __expf(lg[nt][1]-m),
            e2 = __expf(lg[nt][2]-m), e3 = __expf(lg[nt][3]-m);
      float s = e0+e1+e2+e3;
      s += __shfl_xor(s, 16);
      s += __shfl_xor(s, 32);
      float inv = 1.0f / s;
      float pb = pb2s[nt*16 + c16];
      float acc = e0*(vv[nt][0] + pe[nt][0] + pb)
                + e1*(vv[nt][1] + pe[nt][1] + pb)
                + e2*(vv[nt][2] + pe[nt][2] + pb)
                + e3*(vv[nt][3] + pe[nt][3] + pb);
      acc *= inv;
      acc += __shfl_xor(acc, 16);
      acc += __shfl_xor(acc, 32);
      if (lane < 16) out[q*DIM + nt*16 + lane] = acc;
    }
  }
}

// ---------------- launch ----------------
extern "C" void kernel_launch(void* const* d_in, const int* in_sizes, int n_in,
                              void* d_out, int out_size, void* d_ws, size_t ws_size,
                              hipStream_t stream) {
  const float* x   = (const float*)d_in[0];
  const float* pos = (const float*)d_in[1];
  const float* pw1 = (const float*)d_in[2];
  const float* pb1 = (const float*)d_in[3];
  const float* pw2 = (const float*)d_in[4];
  const float* pb2 = (const float*)d_in[5];
  const float* qw  = (const float*)d_in[6];
  const float* qb  = (const float*)d_in[7];
  const float* kw  = (const float*)d_in[8];
  const float* kb  = (const float*)d_in[9];
  const float* vw  = (const float*)d_in[10];
  const float* vb  = (const float*)d_in[11];
  const float* aw1 = (const float*)d_in[12];
  const float* ab1 = (const float*)d_in[13];
  const float* aw2 = (const float*)d_in[14];
  const float* ab2 = (const float*)d_in[15];
  float* out = (float*)d_out;

  char* ws = (char*)d_ws;
  float4* pos4   = (float4*)(ws);                       // 256 KB
  int*    knnIdx = (int*)(ws + (1u<<20));               // 1 MB
  u64*    part   = (u64*)(ws + (2u<<20));               // 16.8 MB (dead after merge)
  float*  vws    = (float*)(ws + (2u<<20));             // 8 MB   (reuse)
  float*  qa     = (float*)(ws + (11u<<20));            // 2 MB
  float*  ka     = (float*)(ws + (13u<<20));            // 2 MB
  char*   wsw    = ws + (19u<<20);                      // weights region
  u16*    pw2T  = (u16*)(wsw);                          // 32 KB
  u16*    w1T   = (u16*)(wsw + 32768);                  // 8 KB
  u16*    aw2T  = (u16*)(wsw + 40960);                  // 8 KB
  float4* pw1q  = (float4*)(wsw + 49152);               // 2 KB
  float*  bias1 = (float*)(wsw + 51200);                // 128 B
  float*  Wq2   = (float*)(wsw + 51328);                // 16 KB
  float*  Wk2   = (float*)(wsw + 67712);                // 16 KB

  prep_pos4<<<NROWS/256, 256, 0, stream>>>(pos, pos4);
  prep_matmul<<<12, 256, 0, stream>>>(pw2, qw, kw, aw1, w1T, Wq2, Wk2);
  prep_convert<<<81, 256, 0, stream>>>(pw2, aw2, pw1, pb1, qb, kb, pb2, aw1, ab1,
                                       pw2T, aw2T, pw1q, bias1);
  knn_scan<<<(NROWS/64)*NCHUNK/4, 256, 0, stream>>>(pos4, part);
  knn_merge<<<NROWS/256, 256, 0, stream>>>(part, knnIdx);
  proj_v<<<NROWS/32, 256, 0, stream>>>(x, vw, vb, Wq2, Wk2, vws, qa, ka);
  attn_mfma<<<NROWS/16, 256, 0, stream>>>(pos4, knnIdx, vws, qa, ka,
                                          pw2T, w1T, aw2T, pw1q, bias1, pb2, ab2, out);
}

// Round 4
// 284.240 us; speedup vs baseline: 3.0153x; 1.0688x over previous
//
#include <hip/hip_runtime.h>
#include <hip/hip_bf16.h>
#include <stdint.h>

#define BATCH 4
#define NPTS  4096
#define DIM   128
#define KNN   16
#define NROWS (BATCH*NPTS)   // 16384
#define NCHUNK 16
#define CHUNK  (NPTS/NCHUNK) // 256

typedef unsigned long long u64;
typedef unsigned int u32;
typedef unsigned short u16;
typedef __attribute__((ext_vector_type(8))) short short8;
typedef __attribute__((ext_vector_type(4))) float f32x4;

__device__ __forceinline__ u16 f2bf(float f) {
  u32 u = __float_as_uint(f);
  u += 0x7FFFu + ((u >> 16) & 1);   // RNE
  return (u16)(u >> 16);
}

// ---------------- prep: pad pos (B,N,3) -> float4 ----------------
__global__ __launch_bounds__(256) void prep_pos4(const float* __restrict__ pos,
                                                 float4* __restrict__ pos4) {
  int i = blockIdx.x * 256 + threadIdx.x;
  if (i < NROWS) pos4[i] = make_float4(pos[3*i], pos[3*i+1], pos[3*i+2], 0.f);
}

// ---------------- prep: folded weight products ----------------
__global__ __launch_bounds__(256) void prep_matmul(
    const float* __restrict__ pw2, const float* __restrict__ qw, const float* __restrict__ kw,
    const float* __restrict__ aw1,
    u16* __restrict__ w1T, float* __restrict__ Wq2, float* __restrict__ Wk2) {
  int p = blockIdx.x >> 2, qtr = blockIdx.x & 3;
  const float* A = p == 0 ? pw2 : (p == 1 ? qw : kw);
  int j = threadIdx.x & 31;
  int r0 = qtr*32 + (threadIdx.x >> 5)*4;
  float acc[4] = {0.f,0.f,0.f,0.f};
  for (int c = 0; c < 128; ++c) {
    float av = aw1[c*32 + j];
#pragma unroll
    for (int rr = 0; rr < 4; ++rr) acc[rr] = fmaf(A[(r0+rr)*128 + c], av, acc[rr]);
  }
#pragma unroll
  for (int rr = 0; rr < 4; ++rr) {
    int h = r0 + rr;
    if (p == 0)      w1T[j*128 + (h ^ ((j&7)<<3))] = f2bf(acc[rr]);
    else if (p == 1) Wq2[h*32 + j] = acc[rr];
    else             Wk2[h*32 + j] = acc[rr];
  }
}

// ---------------- prep: bf16 transposed/swizzled weights + pw1 float4 + bias1 ----------------
__global__ __launch_bounds__(256) void prep_convert(
    const float* __restrict__ pw2, const float* __restrict__ aw2,
    const float* __restrict__ pw1, const float* __restrict__ pb1,
    const float* __restrict__ qb, const float* __restrict__ kb,
    const float* __restrict__ pb2, const float* __restrict__ aw1, const float* __restrict__ ab1,
    u16* __restrict__ pw2T, u16* __restrict__ aw2T,
    float4* __restrict__ pw1q, float* __restrict__ bias1) {
  int bid = blockIdx.x, tid = threadIdx.x;
  if (bid < 64) {
    int e = bid*256 + tid; int k = e >> 7, n = e & 127;
    pw2T[n*128 + (k ^ ((n&7)<<3))] = f2bf(pw2[k*128 + n]);
  } else if (bid < 80) {
    int e = (bid-64)*256 + tid; int k = e >> 7, n = e & 127;
    aw2T[n*32 + (k ^ ((n&3)<<3))] = f2bf(aw2[k*128 + n]);
  } else {
    if (tid < 128) {
      int c = tid;
      pw1q[c ^ ((c & 0x18) >> 2)] = make_float4(pw1[c], pw1[128+c], pw1[256+c], pb1[c]);
    } else if (tid < 160) {
      int j = tid - 128;
      float s = ab1[j];
      for (int c = 0; c < 128; ++c) s += (qb[c]-kb[c]+pb2[c]) * aw1[c*32+j];
      bias1[j] = s;
    }
  }
}

// ---------------- branchless sorting primitives (templated on key type) ----------------
template <typename T>
__device__ __forceinline__ void cex(T& a, T& b) {
  T mn = a < b ? a : b;
  T mx = a < b ? b : a;
  a = mn; b = mx;
}
template <typename T>
__device__ __forceinline__ void sort16(T x[16]) {
#pragma unroll
  for (int k = 2; k <= 16; k <<= 1)
#pragma unroll
    for (int j = k >> 1; j > 0; j >>= 1)
#pragma unroll
      for (int i = 0; i < 16; ++i) {
        int l = i ^ j;
        if (l > i) { if ((i & k) == 0) cex(x[i], x[l]); else cex(x[l], x[i]); }
      }
}
template <typename T>
__device__ __forceinline__ void merge16(T A[16], const T B[16]) {
#pragma unroll
  for (int i = 0; i < 16; ++i) { T b = B[15 - i]; A[i] = A[i] < b ? A[i] : b; }
#pragma unroll
  for (int j = 8; j > 0; j >>= 1)
#pragma unroll
    for (int i = 0; i < 16; ++i) { int l = i ^ j; if (l > i) cex(A[i], A[l]); }
}

// ---------------- kNN pass 1: fp32 u32 keys, per-(query, 256-chunk) top-16 ----------------
// key = (f32 dist bits & ~0xFF) | local_idx(8b). Approximate pre-selection only;
// exact fp64 ordering is restored in knn_refine (superset-safe: see analysis).
__global__ __launch_bounds__(256) void knn_scan(const float4* __restrict__ pos4,
                                                u32* __restrict__ part) {
  __shared__ float4 cs[4][CHUNK];   // 16 KB
  const int lane  = threadIdx.x & 63;
  const int w     = threadIdx.x >> 6;
  const int task  = blockIdx.x * 4 + w;     // 0..4095
  const int qg    = task >> 4;              // 0..255
  const int chunk = task & 15;              // 0..15
  const int qbase = qg * 64;
  const int b     = qbase >> 12;
  const int cbase = chunk * CHUNK;

  const float4* cand = pos4 + b*NPTS + cbase;
#pragma unroll
  for (int i = 0; i < CHUNK/64; ++i) cs[w][lane + 64*i] = cand[lane + 64*i];
  __syncthreads();

  float4 qp = pos4[qbase + lane];
  const float qx = qp.x, qy = qp.y, qz = qp.z;

  u32 best[16];
#pragma unroll
  for (int i = 0; i < 16; ++i) best[i] = ~0u;

#pragma unroll 1
  for (int m = 0; m < CHUNK/16; ++m) {
    u32 batch[16];
#pragma unroll
    for (int e = 0; e < 16; ++e) {
      float4 p = cs[w][m*16 + e];
      float dx = qx - p.x, dy = qy - p.y, dz = qz - p.z;
      float d  = fmaf(dx, dx, fmaf(dy, dy, dz*dz));
      batch[e] = (__float_as_uint(d) & 0xFFFFFF00u) | (u32)(m*16 + e);
    }
    sort16(batch);
    merge16(best, batch);
  }
  const int q = qbase + lane;
#pragma unroll
  for (int s = 0; s < 16; ++s) part[(chunk*16 + s)*NROWS + q] = best[s];
}

// ---------------- kNN pass 2: exact fp64 re-rank + 16-way merge ----------------
// thread = (query qi<16, chunk c<16); per-thread sort16 on the PROVEN fp64 keys,
// then one lane per query merges the 16 sorted lists from LDS.
__global__ __launch_bounds__(256) void knn_refine(const float4* __restrict__ pos4,
                                                  const u32* __restrict__ part,
                                                  int* __restrict__ knnIdx) {
  __shared__ u64 lists[16][273];   // [query][chunk*17+s]; 273-stride -> conflict-free merge
  const int tid = threadIdx.x;
  const int qi = tid >> 4, c = tid & 15;
  const int q = blockIdx.x * 16 + qi;
  const int b = q >> 12;

  float4 qp = pos4[q];
  const double qx = qp.x, qy = qp.y, qz = qp.z;

  u64 key[16];
#pragma unroll
  for (int s = 0; s < 16; ++s) {
    u32 kk = part[(c*16 + s)*NROWS + q];
    int idx = c*CHUNK + (int)(kk & 0xFFu);
    float4 p = pos4[(b<<12) + idx];
    double dx = qx - (double)p.x;
    double dy = qy - (double)p.y;
    double dz = qz - (double)p.z;
    double d  = fma(dx, dx, fma(dy, dy, dz*dz));
    key[s] = (((u64)__double_as_longlong(d)) & ~0xFFFull) | (u64)idx;
  }
  sort16(key);
#pragma unroll
  for (int s = 0; s < 16; ++s) lists[qi][c*17 + s] = key[s];
  __syncthreads();

  if ((tid & 15) == 0) {
    u64 best[16];
#pragma unroll
    for (int s = 0; s < 16; ++s) best[s] = lists[qi][s];
#pragma unroll 1
    for (int cc = 1; cc < 16; ++cc) {
      u64 nb[16];
#pragma unroll
      for (int s = 0; s < 16; ++s) nb[s] = lists[qi][cc*17 + s];
      merge16(best, nb);
    }
    const int outq = q * KNN;
#pragma unroll
    for (int s = 0; s < 16; ++s) knnIdx[outq + s] = (int)(best[s] & 0xFFFull);
  }
}

// ---------------- proj: V + qa + ka ----------------
__global__ __launch_bounds__(256) void proj_v(
    const float* __restrict__ x,
    const float* __restrict__ vw, const float* __restrict__ vb,
    const float* __restrict__ Wq2, const float* __restrict__ Wk2,
    float* __restrict__ vo, float* __restrict__ qa, float* __restrict__ ka) {
  __shared__ float xs[32*DIM];
  const int row0 = blockIdx.x * 32;
  const int tid = threadIdx.x;
  {
    const float4* src = (const float4*)(x + row0*DIM);
    float4* dst = (float4*)xs;
#pragma unroll
    for (int i = 0; i < 4; ++i) dst[tid + 256*i] = src[tid + 256*i];
  }
  __syncthreads();
  { // V
    const int c = tid & 127, g2 = tid >> 7;
    float av[16];
#pragma unroll
    for (int r = 0; r < 16; ++r) av[r] = 0.f;
    for (int d4 = 0; d4 < 32; ++d4) {
      float wv[4];
#pragma unroll
      for (int t = 0; t < 4; ++t) wv[t] = vw[(d4*4+t)*DIM + c];
#pragma unroll
      for (int r = 0; r < 16; ++r) {
        float4 xv = *(const float4*)&xs[(g2*16+r)*DIM + d4*4];
        av[r] = fmaf(xv.x, wv[0], av[r]);
        av[r] = fmaf(xv.y, wv[1], av[r]);
        av[r] = fmaf(xv.z, wv[2], av[r]);
        av[r] = fmaf(xv.w, wv[3], av[r]);
      }
    }
    float bv = vb[c];
#pragma unroll
    for (int r = 0; r < 16; ++r) vo[(row0 + g2*16 + r)*DIM + c] = av[r] + bv;
  }
  { // qa/ka (32 cols)
    const int j = tid & 31, grp = tid >> 5;
    float aq[4] = {0.f,0.f,0.f,0.f}, ak[4] = {0.f,0.f,0.f,0.f};
    for (int d4 = 0; d4 < 32; ++d4) {
#pragma unroll
      for (int t = 0; t < 4; ++t) {
        int d = d4*4 + t;
        float wq = Wq2[d*32 + j], wk = Wk2[d*32 + j];
#pragma unroll
        for (int rr = 0; rr < 4; ++rr) {
          float xv = xs[(grp*4+rr)*DIM + d];
          aq[rr] = fmaf(xv, wq, aq[rr]);
          ak[rr] = fmaf(xv, wk, ak[rr]);
        }
      }
    }
#pragma unroll
    for (int rr = 0; rr < 4; ++rr) {
      qa[(row0 + grp*4 + rr)*32 + j] = aq[rr];
      ka[(row0 + grp*4 + rr)*32 + j] = ak[rr];
    }
  }
}

// ---------------- fused MFMA attention: one wave per query ----------------
__global__ __launch_bounds__(256) void attn_mfma(
    const float4* __restrict__ pos4, const int* __restrict__ knnIdx,
    const float* __restrict__ vws, const float* __restrict__ qa, const float* __restrict__ ka,
    const u16* __restrict__ pw2T, const u16* __restrict__ w1T, const u16* __restrict__ aw2T,
    const float4* __restrict__ pw1q, const float* __restrict__ bias1,
    const float* __restrict__ pb2, const float* __restrict__ ab2,
    float* __restrict__ out) {
  __shared__ __align__(16) u16 pw2s[16384];   // 32 KB
  __shared__ __align__(16) u16 w1s[4096];     // 8 KB
  __shared__ __align__(16) u16 aw2s[4096];    // 8 KB
  __shared__ __align__(16) float4 pw1s[128];  // 2 KB
  __shared__ float bias1s[32];
  __shared__ float pb2s[128];
  __shared__ float ab2s[128];
  __shared__ __align__(16) u16 h2t[4][512];
  __shared__ float4 rels[4][16];
  __shared__ int ids[4][16];

  const int tid = threadIdx.x;
  {
    const uint4* s1 = (const uint4*)pw2T; uint4* d1 = (uint4*)pw2s;
#pragma unroll
    for (int i = 0; i < 8; ++i) d1[tid + 256*i] = s1[tid + 256*i];
    const uint4* s2 = (const uint4*)w1T; uint4* d2 = (uint4*)w1s;
#pragma unroll
    for (int i = 0; i < 2; ++i) d2[tid + 256*i] = s2[tid + 256*i];
    const uint4* s3 = (const uint4*)aw2T; uint4* d3 = (uint4*)aw2s;
#pragma unroll
    for (int i = 0; i < 2; ++i) d3[tid + 256*i] = s3[tid + 256*i];
    if (tid < 128) { pw1s[tid] = pw1q[tid]; pb2s[tid] = pb2[tid]; ab2s[tid] = ab2[tid]; }
    else if (tid < 160) bias1s[tid-128] = bias1[tid-128];
  }
  __syncthreads();

  const int lane = tid & 63, w = tid >> 6;
  const int c16 = lane & 15, g = lane >> 4;

  for (int it = 0; it < 4; ++it) {
    const int q = blockIdx.x*16 + w*4 + it;
    const int b = q >> 12;
    if (lane < 16) {
      int id = knnIdx[q*KNN + lane];
      ids[w][lane] = id;
      float4 pq = pos4[q], pn = pos4[(b<<12) + id];
      rels[w][lane] = make_float4(pq.x-pn.x, pq.y-pn.y, pq.z-pn.z, 0.f);
    }
    __syncthreads();

    int idr[4];
#pragma unroll
    for (int r = 0; r < 4; ++r) idr[r] = ids[w][g*4 + r];

    float qa_v[2], ka_v[2][4];
#pragma unroll
    for (int t = 0; t < 2; ++t) qa_v[t] = qa[q*32 + t*16 + c16];
#pragma unroll
    for (int r = 0; r < 4; ++r)
#pragma unroll
      for (int t = 0; t < 2; ++t) ka_v[t][r] = ka[((b<<12)+idr[r])*32 + t*16 + c16];

    float4 rl = rels[w][c16];
    short8 h1f[4];
#pragma unroll
    for (int kc = 0; kc < 4; ++kc) {
      short8 s;
#pragma unroll
      for (int j = 0; j < 8; ++j) {
        int c = kc*32 + g*8 + j;
        float4 wv = pw1s[c ^ ((c & 0x18) >> 2)];
        float h = fmaf(rl.x, wv.x, fmaf(rl.y, wv.y, fmaf(rl.z, wv.z, wv.w)));
        s[j] = (short)f2bf(fmaxf(h, 0.f));
      }
      h1f[kc] = s;
    }

    f32x4 pe[8];
#pragma unroll
    for (int nt = 0; nt < 8; ++nt) { f32x4 z = {0.f,0.f,0.f,0.f}; pe[nt] = z; }
#pragma unroll
    for (int kc = 0; kc < 4; ++kc)
#pragma unroll
      for (int nt = 0; nt < 8; ++nt) {
        int n = nt*16 + c16;
        short8 bf = *(const short8*)&pw2s[n*128 + ((kc*32 + g*8) ^ ((n&7)<<3))];
        pe[nt] = __builtin_amdgcn_mfma_f32_16x16x32_bf16(h1f[kc], bf, pe[nt], 0, 0, 0);
      }

    f32x4 ha[2];
#pragma unroll
    for (int t = 0; t < 2; ++t) { f32x4 z = {0.f,0.f,0.f,0.f}; ha[t] = z; }
#pragma unroll
    for (int kc = 0; kc < 4; ++kc)
#pragma unroll
      for (int t = 0; t < 2; ++t) {
        int n = t*16 + c16;
        short8 bf = *(const short8*)&w1s[n*128 + ((kc*32 + g*8) ^ ((n&7)<<3))];
        ha[t] = __builtin_amdgcn_mfma_f32_16x16x32_bf16(h1f[kc], bf, ha[t], 0, 0, 0);
      }

#pragma unroll
    for (int t = 0; t < 2; ++t)
#pragma unroll
      for (int r = 0; r < 4; ++r) {
        float v = ha[t][r] + qa_v[t] - ka_v[t][r] + bias1s[t*16 + c16];
        int row = g*4 + r, col = t*16 + c16;
        h2t[w][row*32 + (col ^ ((row&3)<<3))] = f2bf(fmaxf(v, 0.f));
      }
    __syncthreads();

    short8 h2f = *(const short8*)&h2t[w][c16*32 + ((g*8) ^ ((c16&3)<<3))];

    f32x4 lg[8];
#pragma unroll
    for (int nt = 0; nt < 8; ++nt) {
      int n = nt*16 + c16;
      float ab = ab2s[n];
      f32x4 cini = {ab, ab, ab, ab};
      short8 bf = *(const short8*)&aw2s[n*32 + ((g*8) ^ ((n&3)<<3))];
      lg[nt] = __builtin_amdgcn_mfma_f32_16x16x32_bf16(h2f, bf, cini, 0, 0, 0);
    }

    float vv[8][4];
#pragma unroll
    for (int r = 0; r < 4; ++r) {
      const float* vrow = vws + (size_t)((b<<12) + idr[r])*DIM;
#pragma unroll
      for (int nt = 0; nt < 8; ++nt) vv[nt][r] = vrow[nt*16 + c16];
    }

#pragma unroll
    for (int nt = 0; nt < 8; ++nt) {
      float m = fmaxf(fmaxf(lg[nt][0], lg[nt][1]), fmaxf(lg[nt][2], lg[nt][3]));
      m = fmaxf(m, __shfl_xor(m, 16));
      m = fmaxf(m, __shfl_xor(m, 32));
      float e0 = __expf(lg[nt][0]-m), e1 = __expf(lg[nt][1]-m),
            e2 = __expf(lg[nt][2]-m), e3 = __expf(lg[nt][3]-m);
      float s = e0+e1+e2+e3;
      s += __shfl_xor(s, 16);
      s += __shfl_xor(s, 32);
      float inv = 1.0f / s;
      float pb = pb2s[nt*16 + c16];
      float acc = e0*(vv[nt][0] + pe[nt][0] + pb)
                + e1*(vv[nt][1] + pe[nt][1] + pb)
                + e2*(vv[nt][2] + pe[nt][2] + pb)
                + e3*(vv[nt][3] + pe[nt][3] + pb);
      acc *= inv;
      acc += __shfl_xor(acc, 16);
      acc += __shfl_xor(acc, 32);
      if (lane < 16) out[q*DIM + nt*16 + lane] = acc;
    }
  }
}

// ---------------- launch ----------------
extern "C" void kernel_launch(void* const* d_in, const int* in_sizes, int n_in,
                              void* d_out, int out_size, void* d_ws, size_t ws_size,
                              hipStream_t stream) {
  const float* x   = (const float*)d_in[0];
  const float* pos = (const float*)d_in[1];
  const float* pw1 = (const float*)d_in[2];
  const float* pb1 = (const float*)d_in[3];
  const float* pw2 = (const float*)d_in[4];
  const float* pb2 = (const float*)d_in[5];
  const float* qw  = (const float*)d_in[6];
  const float* qb  = (const float*)d_in[7];
  const float* kw  = (const float*)d_in[8];
  const float* kb  = (const float*)d_in[9];
  const float* vw  = (const float*)d_in[10];
  const float* vb  = (const float*)d_in[11];
  const float* aw1 = (const float*)d_in[12];
  const float* ab1 = (const float*)d_in[13];
  const float* aw2 = (const float*)d_in[14];
  const float* ab2 = (const float*)d_in[15];
  float* out = (float*)d_out;

  char* ws = (char*)d_ws;
  float4* pos4   = (float4*)(ws);                       // 256 KB
  int*    knnIdx = (int*)(ws + (1u<<20));               // 1 MB
  u32*    part   = (u32*)(ws + (2u<<20));               // 16 MB (dead after refine)
  float*  vws    = (float*)(ws + (2u<<20));             // 8 MB (reuse)
  float*  qa     = (float*)(ws + (11u<<20));            // 2 MB
  float*  ka     = (float*)(ws + (13u<<20));            // 2 MB
  char*   wsw    = ws + (19u<<20);                      // weights region
  u16*    pw2T  = (u16*)(wsw);                          // 32 KB
  u16*    w1T   = (u16*)(wsw + 32768);                  // 8 KB
  u16*    aw2T  = (u16*)(wsw + 40960);                  // 8 KB
  float4* pw1q  = (float4*)(wsw + 49152);               // 2 KB
  float*  bias1 = (float*)(wsw + 51200);                // 128 B
  float*  Wq2   = (float*)(wsw + 51328);                // 16 KB
  float*  Wk2   = (float*)(wsw + 67712);                // 16 KB

  prep_pos4<<<NROWS/256, 256, 0, stream>>>(pos, pos4);
  prep_matmul<<<12, 256, 0, stream>>>(pw2, qw, kw, aw1, w1T, Wq2, Wk2);
  prep_convert<<<81, 256, 0, stream>>>(pw2, aw2, pw1, pb1, qb, kb, pb2, aw1, ab1,
                                       pw2T, aw2T, pw1q, bias1);
  knn_scan<<<(NROWS/64)*NCHUNK/4, 256, 0, stream>>>(pos4, part);
  knn_refine<<<NROWS/16, 256, 0, stream>>>(pos4, part, knnIdx);
  proj_v<<<NROWS/32, 256, 0, stream>>>(x, vw, vb, Wq2, Wk2, vws, qa, ka);
  attn_mfma<<<NROWS/16, 256, 0, stream>>>(pos4, knnIdx, vws, qa, ka,
                                          pw2T, w1T, aw2T, pw1q, bias1, pb2, ab2, out);
}

// Round 5
// 251.753 us; speedup vs baseline: 3.4044x; 1.1290x over previous
//
#include <hip/hip_runtime.h>
#include <hip/hip_bf16.h>
#include <stdint.h>

#define BATCH 4
#define NPTS  4096
#define DIM   128
#define KNN   16
#define NROWS (BATCH*NPTS)   // 16384
#define NCHUNK 16
#define CHUNK  (NPTS/NCHUNK) // 256

typedef unsigned long long u64;
typedef unsigned int u32;
typedef unsigned short u16;
typedef __attribute__((ext_vector_type(8))) short short8;
typedef __attribute__((ext_vector_type(4))) float f32x4;

__device__ __forceinline__ u16 f2bf(float f) {
  u32 u = __float_as_uint(f);
  u += 0x7FFFu + ((u >> 16) & 1);   // RNE
  return (u16)(u >> 16);
}

// ---------------- prep: pad pos (B,N,3) -> float4 ----------------
__global__ __launch_bounds__(256) void prep_pos4(const float* __restrict__ pos,
                                                 float4* __restrict__ pos4) {
  int i = blockIdx.x * 256 + threadIdx.x;
  if (i < NROWS) pos4[i] = make_float4(pos[3*i], pos[3*i+1], pos[3*i+2], 0.f);
}

// ---------------- prep: folded weight products ----------------
__global__ __launch_bounds__(256) void prep_matmul(
    const float* __restrict__ pw2, const float* __restrict__ qw, const float* __restrict__ kw,
    const float* __restrict__ aw1,
    u16* __restrict__ w1T, float* __restrict__ Wq2, float* __restrict__ Wk2) {
  int p = blockIdx.x >> 2, qtr = blockIdx.x & 3;
  const float* A = p == 0 ? pw2 : (p == 1 ? qw : kw);
  int j = threadIdx.x & 31;
  int r0 = qtr*32 + (threadIdx.x >> 5)*4;
  float acc[4] = {0.f,0.f,0.f,0.f};
  for (int c = 0; c < 128; ++c) {
    float av = aw1[c*32 + j];
#pragma unroll
    for (int rr = 0; rr < 4; ++rr) acc[rr] = fmaf(A[(r0+rr)*128 + c], av, acc[rr]);
  }
#pragma unroll
  for (int rr = 0; rr < 4; ++rr) {
    int h = r0 + rr;
    if (p == 0)      w1T[j*128 + (h ^ ((j&7)<<3))] = f2bf(acc[rr]);
    else if (p == 1) Wq2[h*32 + j] = acc[rr];
    else             Wk2[h*32 + j] = acc[rr];
  }
}

// ---------------- prep: bf16 transposed/swizzled weights + pw1 float4 + bias1 ----------------
__global__ __launch_bounds__(256) void prep_convert(
    const float* __restrict__ pw2, const float* __restrict__ aw2,
    const float* __restrict__ pw1, const float* __restrict__ pb1,
    const float* __restrict__ qb, const float* __restrict__ kb,
    const float* __restrict__ pb2, const float* __restrict__ aw1, const float* __restrict__ ab1,
    u16* __restrict__ pw2T, u16* __restrict__ aw2T,
    float4* __restrict__ pw1q, float* __restrict__ bias1) {
  int bid = blockIdx.x, tid = threadIdx.x;
  if (bid < 64) {
    int e = bid*256 + tid; int k = e >> 7, n = e & 127;
    pw2T[n*128 + (k ^ ((n&7)<<3))] = f2bf(pw2[k*128 + n]);
  } else if (bid < 80) {
    int e = (bid-64)*256 + tid; int k = e >> 7, n = e & 127;
    aw2T[n*32 + (k ^ ((n&3)<<3))] = f2bf(aw2[k*128 + n]);
  } else {
    if (tid < 128) {
      int c = tid;
      pw1q[c ^ ((c & 0x18) >> 2)] = make_float4(pw1[c], pw1[128+c], pw1[256+c], pb1[c]);
    } else if (tid < 160) {
      int j = tid - 128;
      float s = ab1[j];
      for (int c = 0; c < 128; ++c) s += (qb[c]-kb[c]+pb2[c]) * aw1[c*32+j];
      bias1[j] = s;
    }
  }
}

// ---------------- branchless sorting primitives ----------------
template <typename T>
__device__ __forceinline__ void cex(T& a, T& b) {
  T mn = a < b ? a : b;
  T mx = a < b ? b : a;
  a = mn; b = mx;
}
template <typename T>
__device__ __forceinline__ void sort16(T x[16]) {
#pragma unroll
  for (int k = 2; k <= 16; k <<= 1)
#pragma unroll
    for (int j = k >> 1; j > 0; j >>= 1)
#pragma unroll
      for (int i = 0; i < 16; ++i) {
        int l = i ^ j;
        if (l > i) { if ((i & k) == 0) cex(x[i], x[l]); else cex(x[l], x[i]); }
      }
}
template <typename T>
__device__ __forceinline__ void merge16(T A[16], const T B[16]) {
#pragma unroll
  for (int i = 0; i < 16; ++i) { T b = B[15 - i]; A[i] = A[i] < b ? A[i] : b; }
#pragma unroll
  for (int j = 8; j > 0; j >>= 1)
#pragma unroll
    for (int i = 0; i < 16; ++i) { int l = i ^ j; if (l > i) cex(A[i], A[l]); }
}
// sorts a bitonic 32-sequence ascending
__device__ __forceinline__ void bmerge32(u32 x[32]) {
#pragma unroll
  for (int j = 16; j > 0; j >>= 1)
#pragma unroll
    for (int i = 0; i < 32; ++i) { int l = i ^ j; if (l > i) cex(x[i], x[l]); }
}

// ---------------- kNN pass 1: fp32 keys with GLOBAL 12-bit idx; transposed output ----------------
// key = (f32 dist bits & ~0xFFF) | global_idx. Pre-selection only; fp64 re-rank in refine.
__global__ __launch_bounds__(256) void knn_scan(const float4* __restrict__ pos4,
                                                u32* __restrict__ part) {
  __shared__ float4 cs[4][CHUNK];   // 16 KB
  const int lane  = threadIdx.x & 63;
  const int w     = threadIdx.x >> 6;
  const int task  = blockIdx.x * 4 + w;     // 0..4095
  const int qg    = task >> 4;              // 0..255
  const int chunk = task & 15;              // 0..15
  const int qbase = qg * 64;
  const int b     = qbase >> 12;
  const int cbase = chunk * CHUNK;

  const float4* cand = pos4 + b*NPTS + cbase;
#pragma unroll
  for (int i = 0; i < CHUNK/64; ++i) cs[w][lane + 64*i] = cand[lane + 64*i];
  __syncthreads();

  float4 qp = pos4[qbase + lane];
  const float qx = qp.x, qy = qp.y, qz = qp.z;

  u32 best[16];
#pragma unroll
  for (int i = 0; i < 16; ++i) best[i] = ~0u;

#pragma unroll 1
  for (int m = 0; m < CHUNK/16; ++m) {
    u32 batch[16];
#pragma unroll
    for (int e = 0; e < 16; ++e) {
      float4 p = cs[w][m*16 + e];
      float dx = qx - p.x, dy = qy - p.y, dz = qz - p.z;
      float d  = fmaf(dx, dx, fmaf(dy, dy, dz*dz));
      batch[e] = (__float_as_uint(d) & 0xFFFFF000u) | (u32)(cbase + m*16 + e);
    }
    sort16(batch);
    merge16(best, batch);
  }
  // transposed, per-query-contiguous store: part[q*256 + chunk*16 + s]
  const int q = qbase + lane;
  uint4* dst = (uint4*)(part + q*256 + chunk*16);
#pragma unroll
  for (int t = 0; t < 4; ++t)
    dst[t] = make_uint4(best[4*t], best[4*t+1], best[4*t+2], best[4*t+3]);
}

// ---------------- kNN pass 2: u32 keep-32 merge tree + fp64 re-rank of pool ----------------
// block = 256 thr / 16 queries; thread = (qi = tid>>4, c = tid&15).
__global__ __launch_bounds__(256) void knn_refine(const float4* __restrict__ pos4,
                                                  const u32* __restrict__ part,
                                                  int* __restrict__ knnIdx) {
  __shared__ u64 A64[16][137];        // aliased as u32[16][274] for the tree
  __shared__ u32 Bu[16][264];
  u32 (*Au)[274] = (u32 (*)[274])A64;

  const int tid = threadIdx.x;
  const int qi = tid >> 4, c = tid & 15;
  const int q  = blockIdx.x * 16 + qi;
  const int b  = q >> 12;

  // Phase A: coalesced load of own sorted chunk-list -> LDS (17-stride)
  {
    const uint4* src = (const uint4*)(part + q*256 + c*16);
    u32 own[16];
#pragma unroll
    for (int t = 0; t < 4; ++t) {
      uint4 v = src[t];
      own[4*t+0]=v.x; own[4*t+1]=v.y; own[4*t+2]=v.z; own[4*t+3]=v.w;
    }
#pragma unroll
    for (int s = 0; s < 16; ++s) Au[qi][c*17 + s] = own[s];
  }
  __syncthreads();

  // L1: c<8 merge sorted-16 pairs -> sorted-32
  if (c < 8) {
    u32 x[32];
#pragma unroll
    for (int s = 0; s < 16; ++s) x[s]      = Au[qi][(2*c)*17 + s];
#pragma unroll
    for (int s = 0; s < 16; ++s) x[16 + s] = Au[qi][(2*c+1)*17 + 15 - s];
    bmerge32(x);
#pragma unroll
    for (int s = 0; s < 32; ++s) Bu[qi][c*33 + s] = x[s];
  }
  __syncthreads();

  // L2: c<4 keep-32 of sorted-32 pairs
  if (c < 4) {
    u32 x[32];
#pragma unroll
    for (int s = 0; s < 32; ++s) {
      u32 a = Bu[qi][(2*c)*33 + s], bb = Bu[qi][(2*c+1)*33 + 31 - s];
      x[s] = a < bb ? a : bb;
    }
    bmerge32(x);
#pragma unroll
    for (int s = 0; s < 32; ++s) Au[qi][c*33 + s] = x[s];
  }
  __syncthreads();

  // L3: c<2
  if (c < 2) {
    u32 x[32];
#pragma unroll
    for (int s = 0; s < 32; ++s) {
      u32 a = Au[qi][(2*c)*33 + s], bb = Au[qi][(2*c+1)*33 + 31 - s];
      x[s] = a < bb ? a : bb;
    }
    bmerge32(x);
#pragma unroll
    for (int s = 0; s < 32; ++s) Bu[qi][c*33 + s] = x[s];
  }
  __syncthreads();

  // L4: c==0 -> pool32 at Bu[qi][132..163]
  if (c == 0) {
    u32 x[32];
#pragma unroll
    for (int s = 0; s < 32; ++s) {
      u32 a = Bu[qi][s], bb = Bu[qi][33 + 31 - s];
      x[s] = a < bb ? a : bb;
    }
    bmerge32(x);
#pragma unroll
    for (int s = 0; s < 32; ++s) Bu[qi][132 + s] = x[s];
  }
  __syncthreads();

  // Phase C: c<2 fp64 re-rank 16 pool members each (proven key formula)
  if (c < 2) {
    float4 qp = pos4[q];
    const double qx = qp.x, qy = qp.y, qz = qp.z;
    u64 key[16];
#pragma unroll
    for (int s = 0; s < 16; ++s) {
      int idx = (int)(Bu[qi][132 + c*16 + s] & 0xFFFu);
      float4 p = pos4[(b<<12) + idx];
      double dx = qx - (double)p.x;
      double dy = qy - (double)p.y;
      double dz = qz - (double)p.z;
      double d  = fma(dx, dx, fma(dy, dy, dz*dz));
      key[s] = (((u64)__double_as_longlong(d)) & ~0xFFFull) | (u64)idx;
    }
    sort16(key);
#pragma unroll
    for (int s = 0; s < 16; ++s) A64[qi][c*17 + s] = key[s];
  }
  __syncthreads();

  if (c == 0) {
    u64 best[16], nb[16];
#pragma unroll
    for (int s = 0; s < 16; ++s) { best[s] = A64[qi][s]; nb[s] = A64[qi][17 + s]; }
    merge16(best, nb);
    const int outq = q * KNN;
#pragma unroll
    for (int s = 0; s < 16; ++s) knnIdx[outq + s] = (int)(best[s] & 0xFFFull);
  }
}

// ---------------- proj: V + qa + ka ----------------
__global__ __launch_bounds__(256) void proj_v(
    const float* __restrict__ x,
    const float* __restrict__ vw, const float* __restrict__ vb,
    const float* __restrict__ Wq2, const float* __restrict__ Wk2,
    float* __restrict__ vo, float* __restrict__ qa, float* __restrict__ ka) {
  __shared__ float xs[32*DIM];
  const int row0 = blockIdx.x * 32;
  const int tid = threadIdx.x;
  {
    const float4* src = (const float4*)(x + row0*DIM);
    float4* dst = (float4*)xs;
#pragma unroll
    for (int i = 0; i < 4; ++i) dst[tid + 256*i] = src[tid + 256*i];
  }
  __syncthreads();
  { // V
    const int c = tid & 127, g2 = tid >> 7;
    float av[16];
#pragma unroll
    for (int r = 0; r < 16; ++r) av[r] = 0.f;
    for (int d4 = 0; d4 < 32; ++d4) {
      float wv[4];
#pragma unroll
      for (int t = 0; t < 4; ++t) wv[t] = vw[(d4*4+t)*DIM + c];
#pragma unroll
      for (int r = 0; r < 16; ++r) {
        float4 xv = *(const float4*)&xs[(g2*16+r)*DIM + d4*4];
        av[r] = fmaf(xv.x, wv[0], av[r]);
        av[r] = fmaf(xv.y, wv[1], av[r]);
        av[r] = fmaf(xv.z, wv[2], av[r]);
        av[r] = fmaf(xv.w, wv[3], av[r]);
      }
    }
    float bv = vb[c];
#pragma unroll
    for (int r = 0; r < 16; ++r) vo[(row0 + g2*16 + r)*DIM + c] = av[r] + bv;
  }
  { // qa/ka (32 cols)
    const int j = tid & 31, grp = tid >> 5;
    float aq[4] = {0.f,0.f,0.f,0.f}, ak[4] = {0.f,0.f,0.f,0.f};
    for (int d4 = 0; d4 < 32; ++d4) {
#pragma unroll
      for (int t = 0; t < 4; ++t) {
        int d = d4*4 + t;
        float wq = Wq2[d*32 + j], wk = Wk2[d*32 + j];
#pragma unroll
        for (int rr = 0; rr < 4; ++rr) {
          float xv = xs[(grp*4+rr)*DIM + d];
          aq[rr] = fmaf(xv, wq, aq[rr]);
          ak[rr] = fmaf(xv, wk, ak[rr]);
        }
      }
    }
#pragma unroll
    for (int rr = 0; rr < 4; ++rr) {
      qa[(row0 + grp*4 + rr)*32 + j] = aq[rr];
      ka[(row0 + grp*4 + rr)*32 + j] = ak[rr];
    }
  }
}

// ---------------- fused MFMA attention: one wave per query ----------------
__global__ __launch_bounds__(256) void attn_mfma(
    const float4* __restrict__ pos4, const int* __restrict__ knnIdx,
    const float* __restrict__ vws, const float* __restrict__ qa, const float* __restrict__ ka,
    const u16* __restrict__ pw2T, const u16* __restrict__ w1T, const u16* __restrict__ aw2T,
    const float4* __restrict__ pw1q, const float* __restrict__ bias1,
    const float* __restrict__ pb2, const float* __restrict__ ab2,
    float* __restrict__ out) {
  __shared__ __align__(16) u16 pw2s[16384];   // 32 KB
  __shared__ __align__(16) u16 w1s[4096];     // 8 KB
  __shared__ __align__(16) u16 aw2s[4096];    // 8 KB
  __shared__ __align__(16) float4 pw1s[128];  // 2 KB
  __shared__ float bias1s[32];
  __shared__ float pb2s[128];
  __shared__ float ab2s[128];
  __shared__ __align__(16) u16 h2t[4][512];
  __shared__ float4 rels[4][16];
  __shared__ int ids[4][16];

  const int tid = threadIdx.x;
  {
    const uint4* s1 = (const uint4*)pw2T; uint4* d1 = (uint4*)pw2s;
#pragma unroll
    for (int i = 0; i < 8; ++i) d1[tid + 256*i] = s1[tid + 256*i];
    const uint4* s2 = (const uint4*)w1T; uint4* d2 = (uint4*)w1s;
#pragma unroll
    for (int i = 0; i < 2; ++i) d2[tid + 256*i] = s2[tid + 256*i];
    const uint4* s3 = (const uint4*)aw2T; uint4* d3 = (uint4*)aw2s;
#pragma unroll
    for (int i = 0; i < 2; ++i) d3[tid + 256*i] = s3[tid + 256*i];
    if (tid < 128) { pw1s[tid] = pw1q[tid]; pb2s[tid] = pb2[tid]; ab2s[tid] = ab2[tid]; }
    else if (tid < 160) bias1s[tid-128] = bias1[tid-128];
  }
  __syncthreads();

  const int lane = tid & 63, w = tid >> 6;
  const int c16 = lane & 15, g = lane >> 4;

  for (int it = 0; it < 4; ++it) {
    const int q = blockIdx.x*16 + w*4 + it;
    const int b = q >> 12;
    if (lane < 16) {
      int id = knnIdx[q*KNN + lane];
      ids[w][lane] = id;
      float4 pq = pos4[q], pn = pos4[(b<<12) + id];
      rels[w][lane] = make_float4(pq.x-pn.x, pq.y-pn.y, pq.z-pn.z, 0.f);
    }
    __syncthreads();

    int idr[4];
#pragma unroll
    for (int r = 0; r < 4; ++r) idr[r] = ids[w][g*4 + r];

    float qa_v[2], ka_v[2][4];
#pragma unroll
    for (int t = 0; t < 2; ++t) qa_v[t] = qa[q*32 + t*16 + c16];
#pragma unroll
    for (int r = 0; r < 4; ++r)
#pragma unroll
      for (int t = 0; t < 2; ++t) ka_v[t][r] = ka[((b<<12)+idr[r])*32 + t*16 + c16];

    float4 rl = rels[w][c16];
    short8 h1f[4];
#pragma unroll
    for (int kc = 0; kc < 4; ++kc) {
      short8 s;
#pragma unroll
      for (int j = 0; j < 8; ++j) {
        int c = kc*32 + g*8 + j;
        float4 wv = pw1s[c ^ ((c & 0x18) >> 2)];
        float h = fmaf(rl.x, wv.x, fmaf(rl.y, wv.y, fmaf(rl.z, wv.z, wv.w)));
        s[j] = (short)f2bf(fmaxf(h, 0.f));
      }
      h1f[kc] = s;
    }

    f32x4 pe[8];
#pragma unroll
    for (int nt = 0; nt < 8; ++nt) { f32x4 z = {0.f,0.f,0.f,0.f}; pe[nt] = z; }
#pragma unroll
    for (int kc = 0; kc < 4; ++kc)
#pragma unroll
      for (int nt = 0; nt < 8; ++nt) {
        int n = nt*16 + c16;
        short8 bf = *(const short8*)&pw2s[n*128 + ((kc*32 + g*8) ^ ((n&7)<<3))];
        pe[nt] = __builtin_amdgcn_mfma_f32_16x16x32_bf16(h1f[kc], bf, pe[nt], 0, 0, 0);
      }

    f32x4 ha[2];
#pragma unroll
    for (int t = 0; t < 2; ++t) { f32x4 z = {0.f,0.f,0.f,0.f}; ha[t] = z; }
#pragma unroll
    for (int kc = 0; kc < 4; ++kc)
#pragma unroll
      for (int t = 0; t < 2; ++t) {
        int n = t*16 + c16;
        short8 bf = *(const short8*)&w1s[n*128 + ((kc*32 + g*8) ^ ((n&7)<<3))];
        ha[t] = __builtin_amdgcn_mfma_f32_16x16x32_bf16(h1f[kc], bf, ha[t], 0, 0, 0);
      }

#pragma unroll
    for (int t = 0; t < 2; ++t)
#pragma unroll
      for (int r = 0; r < 4; ++r) {
        float v = ha[t][r] + qa_v[t] - ka_v[t][r] + bias1s[t*16 + c16];
        int row = g*4 + r, col = t*16 + c16;
        h2t[w][row*32 + (col ^ ((row&3)<<3))] = f2bf(fmaxf(v, 0.f));
      }
    __syncthreads();

    short8 h2f = *(const short8*)&h2t[w][c16*32 + ((g*8) ^ ((c16&3)<<3))];

    f32x4 lg[8];
#pragma unroll
    for (int nt = 0; nt < 8; ++nt) {
      int n = nt*16 + c16;
      float ab = ab2s[n];
      f32x4 cini = {ab, ab, ab, ab};
      short8 bf = *(const short8*)&aw2s[n*32 + ((g*8) ^ ((n&3)<<3))];
      lg[nt] = __builtin_amdgcn_mfma_f32_16x16x32_bf16(h2f, bf, cini, 0, 0, 0);
    }

    float vv[8][4];
#pragma unroll
    for (int r = 0; r < 4; ++r) {
      const float* vrow = vws + (size_t)((b<<12) + idr[r])*DIM;
#pragma unroll
      for (int nt = 0; nt < 8; ++nt) vv[nt][r] = vrow[nt*16 + c16];
    }

#pragma unroll
    for (int nt = 0; nt < 8; ++nt) {
      float m = fmaxf(fmaxf(lg[nt][0], lg[nt][1]), fmaxf(lg[nt][2], lg[nt][3]));
      m = fmaxf(m, __shfl_xor(m, 16));
      m = fmaxf(m, __shfl_xor(m, 32));
      float e0 = __expf(lg[nt][0]-m), e1 = __expf(lg[nt][1]-m),
            e2 = __expf(lg[nt][2]-m), e3 = __expf(lg[nt][3]-m);
      float s = e0+e1+e2+e3;
      s += __shfl_xor(s, 16);
      s += __shfl_xor(s, 32);
      float inv = 1.0f / s;
      float pb = pb2s[nt*16 + c16];
      float acc = e0*(vv[nt][0] + pe[nt][0] + pb)
                + e1*(vv[nt][1] + pe[nt][1] + pb)
                + e2*(vv[nt][2] + pe[nt][2] + pb)
                + e3*(vv[nt][3] + pe[nt][3] + pb);
      acc *= inv;
      acc += __shfl_xor(acc, 16);
      acc += __shfl_xor(acc, 32);
      if (lane < 16) out[q*DIM + nt*16 + lane] = acc;
    }
  }
}

// ---------------- launch ----------------
extern "C" void kernel_launch(void* const* d_in, const int* in_sizes, int n_in,
                              void* d_out, int out_size, void* d_ws, size_t ws_size,
                              hipStream_t stream) {
  const float* x   = (const float*)d_in[0];
  const float* pos = (const float*)d_in[1];
  const float* pw1 = (const float*)d_in[2];
  const float* pb1 = (const float*)d_in[3];
  const float* pw2 = (const float*)d_in[4];
  const float* pb2 = (const float*)d_in[5];
  const float* qw  = (const float*)d_in[6];
  const float* qb  = (const float*)d_in[7];
  const float* kw  = (const float*)d_in[8];
  const float* kb  = (const float*)d_in[9];
  const float* vw  = (const float*)d_in[10];
  const float* vb  = (const float*)d_in[11];
  const float* aw1 = (const float*)d_in[12];
  const float* ab1 = (const float*)d_in[13];
  const float* aw2 = (const float*)d_in[14];
  const float* ab2 = (const float*)d_in[15];
  float* out = (float*)d_out;

  char* ws = (char*)d_ws;
  float4* pos4   = (float4*)(ws);                       // 256 KB
  int*    knnIdx = (int*)(ws + (1u<<20));               // 1 MB
  u32*    part   = (u32*)(ws + (2u<<20));               // 16 MB (dead after refine)
  float*  vws    = (float*)(ws + (2u<<20));             // 8 MB (reuse)
  float*  qa     = (float*)(ws + (11u<<20));            // 2 MB
  float*  ka     = (float*)(ws + (13u<<20));            // 2 MB
  char*   wsw    = ws + (19u<<20);                      // weights region
  u16*    pw2T  = (u16*)(wsw);                          // 32 KB
  u16*    w1T   = (u16*)(wsw + 32768);                  // 8 KB
  u16*    aw2T  = (u16*)(wsw + 40960);                  // 8 KB
  float4* pw1q  = (float4*)(wsw + 49152);               // 2 KB
  float*  bias1 = (float*)(wsw + 51200);                // 128 B
  float*  Wq2   = (float*)(wsw + 51328);                // 16 KB
  float*  Wk2   = (float*)(wsw + 67712);                // 16 KB

  prep_pos4<<<NROWS/256, 256, 0, stream>>>(pos, pos4);
  prep_matmul<<<12, 256, 0, stream>>>(pw2, qw, kw, aw1, w1T, Wq2, Wk2);
  prep_convert<<<81, 256, 0, stream>>>(pw2, aw2, pw1, pb1, qb, kb, pb2, aw1, ab1,
                                       pw2T, aw2T, pw1q, bias1);
  knn_scan<<<(NROWS/64)*NCHUNK/4, 256, 0, stream>>>(pos4, part);
  knn_refine<<<NROWS/16, 256, 0, stream>>>(pos4, part, knnIdx);
  proj_v<<<NROWS/32, 256, 0, stream>>>(x, vw, vb, Wq2, Wk2, vws, qa, ka);
  attn_mfma<<<NROWS/16, 256, 0, stream>>>(pos4, knnIdx, vws, qa, ka,
                                          pw2T, w1T, aw2T, pw1q, bias1, pb2, ab2, out);
}